// Round 2
// baseline (254.829 us; speedup 1.0000x reference)
//
#include <hip/hip_runtime.h>
#include <hip/hip_bf16.h>

typedef __attribute__((ext_vector_type(4))) float f32x4;
typedef __attribute__((ext_vector_type(8))) short bf16x8;

// Problem constants (B=2, S=2048, D=1024, H=16, DK=64)
#define Bn 2
#define Sn 2048
#define Dn 1024
#define Hn 16
#define DKn 64
#define Mrows (Bn * Sn)   // 4096

__device__ __forceinline__ unsigned short f2bf(float f) {
  unsigned int x = __float_as_uint(f);
  x += 0x7fffu + ((x >> 16) & 1u);   // round-to-nearest-even
  return (unsigned short)(x >> 16);
}

__device__ __forceinline__ f32x4 mfma16(bf16x8 a, bf16x8 b, f32x4 c) {
  return __builtin_amdgcn_mfma_f32_16x16x32_bf16(a, b, c, 0, 0, 0);
}

__device__ __forceinline__ void gload_lds16(const unsigned short* g, unsigned short* l) {
  __builtin_amdgcn_global_load_lds(
      (const __attribute__((address_space(1))) void*)g,
      (__attribute__((address_space(3))) void*)l, 16, 0, 0);
}

// ---------------------------------------------------------------------------
// fp32 -> bf16 convert (memory-bound, vectorized)
// ---------------------------------------------------------------------------
__global__ __launch_bounds__(256)
void cvt_f32_bf16(const float* __restrict__ in, unsigned short* __restrict__ out, int n) {
  int i = (blockIdx.x * 256 + threadIdx.x) * 4;
  if (i >= n) return;
  float4 v = *(const float4*)(in + i);
  ushort4 o;
  o.x = f2bf(v.x); o.y = f2bf(v.y); o.z = f2bf(v.z); o.w = f2bf(v.w);
  *(ushort4*)(out + i) = o;
}

// ---------------------------------------------------------------------------
// GEMM: C[M,N] = A[M,K] * W[N,K]^T  (bf16 in, fp32 accum, bf16 or fp32 out)
// M=4096, N=1024, K=1024.  128x128 tile, BK=64, 4 waves, m97 structure.
// ---------------------------------------------------------------------------
template<bool OUTF32>
__device__ __forceinline__ void gemm_body(const unsigned short* __restrict__ A,
                                          const unsigned short* __restrict__ W,
                                          unsigned short* __restrict__ Cb,
                                          float* __restrict__ Cf) {
  const int K = Dn, N = Dn;
  __shared__ unsigned short As[128 * 64];
  __shared__ unsigned short Bs[128 * 64];
  const int tid  = threadIdx.x;
  const int wid  = tid >> 6;
  const int lane = tid & 63;
  const int l15  = lane & 15;
  const int lg   = lane >> 4;
  const int row0 = blockIdx.x * 128;
  const int col0 = blockIdx.y * 128;
  const int wr = (wid >> 1) * 64;
  const int wc = (wid & 1) * 64;

  f32x4 acc[4][4] = {};

  const int srow = lane >> 3;          // 0..7 within a 1KB chunk
  const int scol = (lane & 7) * 8;     // element col, 16B granules

  for (int kt = 0; kt < K; kt += 64) {
#pragma unroll
    for (int p = 0; p < 4; ++p) {
      int chunk = p * 4 + wid;                       // 0..15
      int r = chunk * 8 + srow;
      gload_lds16(A + (size_t)(row0 + r) * K + kt + scol, &As[chunk * 512]);
    }
#pragma unroll
    for (int p = 0; p < 4; ++p) {
      int chunk = p * 4 + wid;
      int r = chunk * 8 + srow;
      gload_lds16(W + (size_t)(col0 + r) * K + kt + scol, &Bs[chunk * 512]);
    }
    __syncthreads();

#pragma unroll
    for (int kk = 0; kk < 2; ++kk) {
      bf16x8 af[4], bfr[4];
#pragma unroll
      for (int m = 0; m < 4; ++m)
        af[m] = *(const bf16x8*)(&As[(wr + m * 16 + l15) * 64 + kk * 32 + lg * 8]);
#pragma unroll
      for (int n = 0; n < 4; ++n)
        bfr[n] = *(const bf16x8*)(&Bs[(wc + n * 16 + l15) * 64 + kk * 32 + lg * 8]);
#pragma unroll
      for (int m = 0; m < 4; ++m)
#pragma unroll
        for (int n = 0; n < 4; ++n)
          acc[m][n] = mfma16(af[m], bfr[n], acc[m][n]);
    }
    __syncthreads();
  }

  // Epilogue: C/D layout col = lane&15, row = (lane>>4)*4 + j  [m89 verified]
#pragma unroll
  for (int m = 0; m < 4; ++m)
#pragma unroll
    for (int n = 0; n < 4; ++n) {
      int r0 = row0 + wr + m * 16 + lg * 4;
      int c  = col0 + wc + n * 16 + l15;
#pragma unroll
      for (int j = 0; j < 4; ++j) {
        size_t idx = (size_t)(r0 + j) * N + c;
        if (OUTF32) Cf[idx] = acc[m][n][j];
        else        Cb[idx] = f2bf(acc[m][n][j]);
      }
    }
}

__global__ __launch_bounds__(256)
void gemm_qkv(const unsigned short* __restrict__ A,
              const unsigned short* __restrict__ W0,
              const unsigned short* __restrict__ W1,
              const unsigned short* __restrict__ W2,
              unsigned short* __restrict__ C0,
              unsigned short* __restrict__ C1,
              unsigned short* __restrict__ C2) {
  const unsigned short* W = (blockIdx.z == 0) ? W0 : ((blockIdx.z == 1) ? W1 : W2);
  unsigned short* C       = (blockIdx.z == 0) ? C0 : ((blockIdx.z == 1) ? C1 : C2);
  gemm_body<false>(A, W, C, nullptr);
}

__global__ __launch_bounds__(256)
void gemm_out(const unsigned short* __restrict__ A,
              const unsigned short* __restrict__ W,
              float* __restrict__ C) {
  gemm_body<true>(A, W, nullptr, C);
}

// ---------------------------------------------------------------------------
// Flash attention (causal).  Q/K/V in [B*S, D] bf16, head slice stride DKn.
// Block: 64 Q rows of one (b,h); 4 waves x 16 rows.  K-tiles of 64.
// K tile is XOR-swizzled (pre-swizzled global source + swizzled ds_read) to
// kill the 16-way bank conflict of the row-major 128B-stride layout.
// ---------------------------------------------------------------------------
__global__ __launch_bounds__(256)
void attn_fwd(const unsigned short* __restrict__ Qg,
              const unsigned short* __restrict__ Kg,
              const unsigned short* __restrict__ Vg,
              unsigned short* __restrict__ Og) {
  const int qt  = blockIdx.x;        // 0..31
  const int bh  = blockIdx.y;        // 0..31
  const int bb  = bh >> 4;
  const int hh  = bh & 15;
  const int tid = threadIdx.x, wid = tid >> 6, lane = tid & 63;
  const int l15 = lane & 15, lg = lane >> 4;
  const int q0  = qt * 64;
  const int wq  = wid * 16;
  const size_t base = (size_t)bb * Sn * Dn + (size_t)hh * DKn;

  __shared__ unsigned short Ks[64 * 64];      // K tile [key][d], XOR-swizzled granules
  __shared__ unsigned short Vt[64 * 72];      // V^T    [d][key], pad to 72
  __shared__ unsigned short Ps[4][16 * 72];   // per-wave P, pad to 72

  // Q fragments (A-operand layout: row = l15, k = lg*8 + r)
  bf16x8 qf[2];
#pragma unroll
  for (int kk = 0; kk < 2; ++kk)
    qf[kk] = *(const bf16x8*)(Qg + base +
              (size_t)(q0 + wq + l15) * Dn + kk * 32 + lg * 8);

  f32x4 oacc[4] = {};
  float mrun[4], lrun[4];
#pragma unroll
  for (int j = 0; j < 4; ++j) { mrun[j] = -1e30f; lrun[j] = 0.f; }

  const float scale = 0.125f;               // 1/sqrt(64)
  const int lrow = lane >> 3;               // staging row-within-chunk 0..7
  const int sgran = (lane & 7) ^ lrow;      // pre-swizzled source granule

  for (int kt = 0; kt <= qt; ++kt) {
    const int k0 = kt << 6;

    // stage K tile (global_load_lds, linear dest, swizzled source granule)
#pragma unroll
    for (int p = 0; p < 2; ++p) {
      int chunk = p * 4 + wid;              // 0..7
      int r = chunk * 8 + lrow;
      gload_lds16(Kg + base + (size_t)(k0 + r) * Dn + sgran * 8, &Ks[chunk * 512]);
    }
    // stage V transposed: read [key][d] coalesced, write Vt[d][key]
#pragma unroll
    for (int p = 0; p < 2; ++p) {
      int e = (p * 256 + tid) * 8;
      int r = e >> 6, c = e & 63;
      union { int4 v; unsigned short u[8]; } un;
      un.v = *(const int4*)(Vg + base + (size_t)(k0 + r) * Dn + c);
#pragma unroll
      for (int i = 0; i < 8; ++i) Vt[(c + i) * 72 + r] = un.u[i];
    }
    __syncthreads();

    // S = Q K^T  (B-operand: B[k][col] = K[col_key][d]; swizzled granule read)
    f32x4 sf[4] = {};
#pragma unroll
    for (int kn = 0; kn < 4; ++kn) {
      int g0 = (lg ^ (l15 & 7)) * 8;
      int g1 = ((4 | lg) ^ (l15 & 7)) * 8;
      bf16x8 kf0 = *(const bf16x8*)(&Ks[(kn * 16 + l15) * 64 + g0]);
      bf16x8 kf1 = *(const bf16x8*)(&Ks[(kn * 16 + l15) * 64 + g1]);
      sf[kn] = mfma16(qf[0], kf0, sf[kn]);
      sf[kn] = mfma16(qf[1], kf1, sf[kn]);
    }
    const bool needmask = (kt == qt);
    // scale + causal mask
#pragma unroll
    for (int kn = 0; kn < 4; ++kn)
#pragma unroll
      for (int j = 0; j < 4; ++j) {
        float v = sf[kn][j] * scale;
        if (needmask) {
          int rg = q0 + wq + lg * 4 + j;
          int cg = k0 + kn * 16 + l15;
          if (cg > rg) v = -1e30f;
        }
        sf[kn][j] = v;
      }
    // row max (16-lane groups hold one row's 16 cols per kn frag)
    float pm[4];
#pragma unroll
    for (int j = 0; j < 4; ++j) {
      float t = fmaxf(fmaxf(sf[0][j], sf[1][j]), fmaxf(sf[2][j], sf[3][j]));
      t = fmaxf(t, __shfl_xor(t, 1, 16));
      t = fmaxf(t, __shfl_xor(t, 2, 16));
      t = fmaxf(t, __shfl_xor(t, 4, 16));
      t = fmaxf(t, __shfl_xor(t, 8, 16));
      pm[j] = t;
    }
    // online-softmax update
#pragma unroll
    for (int j = 0; j < 4; ++j) {
      float mnew = fmaxf(mrun[j], pm[j]);
      float corr = __expf(mrun[j] - mnew);
      mrun[j] = mnew;
      lrun[j] *= corr;
#pragma unroll
      for (int dn = 0; dn < 4; ++dn) oacc[dn][j] *= corr;
    }
    // P = exp(S - m), row sums
    float rs[4] = {};
#pragma unroll
    for (int kn = 0; kn < 4; ++kn)
#pragma unroll
      for (int j = 0; j < 4; ++j) {
        float p = __expf(sf[kn][j] - mrun[j]);
        sf[kn][j] = p;
        rs[j] += p;
      }
#pragma unroll
    for (int j = 0; j < 4; ++j) {
      float t = rs[j];
      t += __shfl_xor(t, 1, 16);
      t += __shfl_xor(t, 2, 16);
      t += __shfl_xor(t, 4, 16);
      t += __shfl_xor(t, 8, 16);
      lrun[j] += t;
    }
    // P (C-layout) -> LDS -> A-layout for PV
#pragma unroll
    for (int kn = 0; kn < 4; ++kn)
#pragma unroll
      for (int j = 0; j < 4; ++j)
        Ps[wid][(lg * 4 + j) * 72 + kn * 16 + l15] = f2bf(sf[kn][j]);
    // O += P V
#pragma unroll
    for (int kk = 0; kk < 2; ++kk) {
      bf16x8 pf = *(const bf16x8*)(&Ps[wid][l15 * 72 + kk * 32 + lg * 8]);
#pragma unroll
      for (int dn = 0; dn < 4; ++dn) {
        bf16x8 vf = *(const bf16x8*)(&Vt[(dn * 16 + l15) * 72 + kk * 32 + lg * 8]);
        oacc[dn] = mfma16(pf, vf, oacc[dn]);
      }
    }
    __syncthreads();
  }

  // epilogue: O /= l, write bf16
#pragma unroll
  for (int dn = 0; dn < 4; ++dn)
#pragma unroll
    for (int j = 0; j < 4; ++j) {
      float v = oacc[dn][j] / lrun[j];
      int row = q0 + wq + lg * 4 + j;
      Og[base + (size_t)row * Dn + dn * 16 + l15] = f2bf(v);
    }
}

// ---------------------------------------------------------------------------
extern "C" void kernel_launch(void* const* d_in, const int* in_sizes, int n_in,
                              void* d_out, int out_size, void* d_ws, size_t ws_size,
                              hipStream_t stream) {
  const float* x  = (const float*)d_in[0];
  const float* Wq = (const float*)d_in[1];
  const float* Wk = (const float*)d_in[2];
  const float* Wv = (const float*)d_in[3];
  const float* Wo = (const float*)d_in[4];
  float* out = (float*)d_out;

  char* ws = (char*)d_ws;
  size_t off = 0;
  unsigned short* xb  = (unsigned short*)(ws + off); off += (size_t)Mrows * Dn * 2;
  unsigned short* wqb = (unsigned short*)(ws + off); off += (size_t)Dn * Dn * 2;
  unsigned short* wkb = (unsigned short*)(ws + off); off += (size_t)Dn * Dn * 2;
  unsigned short* wvb = (unsigned short*)(ws + off); off += (size_t)Dn * Dn * 2;
  unsigned short* wob = (unsigned short*)(ws + off); off += (size_t)Dn * Dn * 2;
  unsigned short* Qb  = (unsigned short*)(ws + off); off += (size_t)Mrows * Dn * 2;
  unsigned short* Kb  = (unsigned short*)(ws + off); off += (size_t)Mrows * Dn * 2;
  unsigned short* Vb  = (unsigned short*)(ws + off); off += (size_t)Mrows * Dn * 2;
  unsigned short* Ob  = (unsigned short*)(ws + off); off += (size_t)Mrows * Dn * 2;

  const int nx = Mrows * Dn;       // 4194304
  const int nw = Dn * Dn;          // 1048576
  cvt_f32_bf16<<<nx / 4 / 256, 256, 0, stream>>>(x,  xb,  nx);
  cvt_f32_bf16<<<nw / 4 / 256, 256, 0, stream>>>(Wq, wqb, nw);
  cvt_f32_bf16<<<nw / 4 / 256, 256, 0, stream>>>(Wk, wkb, nw);
  cvt_f32_bf16<<<nw / 4 / 256, 256, 0, stream>>>(Wv, wvb, nw);
  cvt_f32_bf16<<<nw / 4 / 256, 256, 0, stream>>>(Wo, wob, nw);

  gemm_qkv<<<dim3(Mrows / 128, Dn / 128, 3), 256, 0, stream>>>(xb, wqb, wkb, wvb, Qb, Kb, Vb);
  attn_fwd<<<dim3(Sn / 64, Bn * Hn), 256, 0, stream>>>(Qb, Kb, Vb, Ob);
  gemm_out<<<dim3(Mrows / 128, Dn / 128), 256, 0, stream>>>(Ob, wob, out);
}

// Round 3
// 174.627 us; speedup vs baseline: 1.4593x; 1.4593x over previous
//
#include <hip/hip_runtime.h>
#include <hip/hip_bf16.h>

typedef __attribute__((ext_vector_type(4))) float f32x4;
typedef __attribute__((ext_vector_type(8))) short bf16x8;

// Problem constants (B=2, S=2048, D=1024, H=16, DK=64)
#define Bn 2
#define Sn 2048
#define Dn 1024
#define Hn 16
#define DKn 64
#define Mrows (Bn * Sn)   // 4096

__device__ __forceinline__ unsigned short f2bf(float f) {
  unsigned int x = __float_as_uint(f);
  x += 0x7fffu + ((x >> 16) & 1u);   // round-to-nearest-even
  return (unsigned short)(x >> 16);
}

__device__ __forceinline__ f32x4 mfma16(bf16x8 a, bf16x8 b, f32x4 c) {
  return __builtin_amdgcn_mfma_f32_16x16x32_bf16(a, b, c, 0, 0, 0);
}

__device__ __forceinline__ void gload_lds16(const unsigned short* g, unsigned short* l) {
  __builtin_amdgcn_global_load_lds(
      (const __attribute__((address_space(1))) void*)g,
      (__attribute__((address_space(3))) void*)l, 16, 0, 0);
}

// ---------------------------------------------------------------------------
// fused fp32 -> bf16 convert for x + 4 weights (one launch)
// region by i>>20: 0..3 = x (4M elems), 4..7 = Wq,Wk,Wv,Wo (1M each)
// ---------------------------------------------------------------------------
__global__ __launch_bounds__(256)
void cvt_all(const float* __restrict__ x,  const float* __restrict__ wq,
             const float* __restrict__ wk, const float* __restrict__ wv,
             const float* __restrict__ wo,
             unsigned short* __restrict__ xb,  unsigned short* __restrict__ wqb,
             unsigned short* __restrict__ wkb, unsigned short* __restrict__ wvb,
             unsigned short* __restrict__ wob) {
  int i = (blockIdx.x * 256 + threadIdx.x) * 4;
  const float* src; unsigned short* dst; int off;
  int r = i >> 20;
  if (r < 4)       { src = x;  dst = xb;  off = i; }
  else if (r == 4) { src = wq; dst = wqb; off = i & 1048575; }
  else if (r == 5) { src = wk; dst = wkb; off = i & 1048575; }
  else if (r == 6) { src = wv; dst = wvb; off = i & 1048575; }
  else             { src = wo; dst = wob; off = i & 1048575; }
  float4 v = *(const float4*)(src + off);
  ushort4 o;
  o.x = f2bf(v.x); o.y = f2bf(v.y); o.z = f2bf(v.z); o.w = f2bf(v.w);
  *(ushort4*)(dst + off) = o;
}

// ---------------------------------------------------------------------------
// GEMM: C[M,N] = A[M,K] * W[N,K]^T  (bf16 in, fp32 accum)
// MODE 0: bf16 row-major, scaled by 0.125 (Q, pre-scaled by 1/sqrt(dk))
// MODE 1: bf16 row-major (K)
// MODE 2: bf16 transposed-V layout Vt[b][h][d][s] (packed 8B stores)
// MODE 3: fp32 row-major (final output)
// ---------------------------------------------------------------------------
template<int MODE>
__device__ __forceinline__ void gemm_body(const unsigned short* __restrict__ A,
                                          const unsigned short* __restrict__ W,
                                          unsigned short* __restrict__ Cb,
                                          float* __restrict__ Cf) {
  const int K = Dn, N = Dn;
  __shared__ unsigned short As[128 * 64];
  __shared__ unsigned short Bs[128 * 64];
  const int tid  = threadIdx.x;
  const int wid  = tid >> 6;
  const int lane = tid & 63;
  const int l15  = lane & 15;
  const int lg   = lane >> 4;
  const int row0 = blockIdx.x * 128;
  const int col0 = blockIdx.y * 128;
  const int wr = (wid >> 1) * 64;
  const int wc = (wid & 1) * 64;

  f32x4 acc[4][4] = {};

  const int srow = lane >> 3;          // 0..7 within a 1KB chunk
  const int scol = (lane & 7) * 8;     // element col, 16B granules

  for (int kt = 0; kt < K; kt += 64) {
#pragma unroll
    for (int p = 0; p < 4; ++p) {
      int chunk = p * 4 + wid;                       // 0..15
      int r = chunk * 8 + srow;
      gload_lds16(A + (size_t)(row0 + r) * K + kt + scol, &As[chunk * 512]);
    }
#pragma unroll
    for (int p = 0; p < 4; ++p) {
      int chunk = p * 4 + wid;
      int r = chunk * 8 + srow;
      gload_lds16(W + (size_t)(col0 + r) * K + kt + scol, &Bs[chunk * 512]);
    }
    __syncthreads();

#pragma unroll
    for (int kk = 0; kk < 2; ++kk) {
      bf16x8 af[4], bfr[4];
#pragma unroll
      for (int m = 0; m < 4; ++m)
        af[m] = *(const bf16x8*)(&As[(wr + m * 16 + l15) * 64 + kk * 32 + lg * 8]);
#pragma unroll
      for (int n = 0; n < 4; ++n)
        bfr[n] = *(const bf16x8*)(&Bs[(wc + n * 16 + l15) * 64 + kk * 32 + lg * 8]);
#pragma unroll
      for (int m = 0; m < 4; ++m)
#pragma unroll
        for (int n = 0; n < 4; ++n)
          acc[m][n] = mfma16(af[m], bfr[n], acc[m][n]);
    }
    __syncthreads();
  }

  // Epilogue: C/D layout col = lane&15, row = (lane>>4)*4 + j  [m89 verified]
#pragma unroll
  for (int m = 0; m < 4; ++m)
#pragma unroll
    for (int n = 0; n < 4; ++n) {
      int r0 = row0 + wr + m * 16 + lg * 4;
      int c  = col0 + wc + n * 16 + l15;
      if (MODE == 2) {
        // V transposed: Vt[((b*H + h)*DK + d)][s], s = token & 2047
        int b = r0 >> 11, s = r0 & 2047;
        int h = c >> 6,  d = c & 63;
        ushort4 pw;
        pw.x = f2bf(acc[m][n][0]); pw.y = f2bf(acc[m][n][1]);
        pw.z = f2bf(acc[m][n][2]); pw.w = f2bf(acc[m][n][3]);
        *(ushort4*)(Cb + ((((size_t)b * Hn + h) * DKn + d) << 11) + s) = pw;
      } else {
#pragma unroll
        for (int j = 0; j < 4; ++j) {
          size_t idx = (size_t)(r0 + j) * N + c;
          float v = acc[m][n][j];
          if (MODE == 3)      Cf[idx] = v;
          else if (MODE == 0) Cb[idx] = f2bf(v * 0.125f);
          else                Cb[idx] = f2bf(v);
        }
      }
    }
}

__global__ __launch_bounds__(256)
void gemm_qkv(const unsigned short* __restrict__ A,
              const unsigned short* __restrict__ W0,
              const unsigned short* __restrict__ W1,
              const unsigned short* __restrict__ W2,
              unsigned short* __restrict__ C0,
              unsigned short* __restrict__ C1,
              unsigned short* __restrict__ C2) {
  if (blockIdx.z == 0)      gemm_body<0>(A, W0, C0, nullptr);
  else if (blockIdx.z == 1) gemm_body<1>(A, W1, C1, nullptr);
  else                      gemm_body<2>(A, W2, C2, nullptr);
}

__global__ __launch_bounds__(256)
void gemm_out(const unsigned short* __restrict__ A,
              const unsigned short* __restrict__ W,
              float* __restrict__ C) {
  gemm_body<3>(A, W, nullptr, C);
}

// ---------------------------------------------------------------------------
// Flash attention (causal), swapped-operand form.
// Q pre-scaled by 1/sqrt(dk).  Q/K row-major [token][D]; V pre-transposed
// Vt[b][h][d][s].  Block: 128 q rows of one (b,h); 4 waves x 32 rows.
// KV tile = 64.  S^T = mfma(K, Q): lane's q = qm*16 + (lane&15) -> softmax
// is lane-local (in-register tree + 2 shfl_xor).  PV as mfma(Vt, P) -> O^T
// fragments, also lane-local through the epilogue.  P round-trips through
// per-wave LDS with packed b64 writes.  K/Vt staged via global_load_lds with
// XOR source-granule swizzle (linear LDS dest, rule #21).
// ---------------------------------------------------------------------------
__global__ __launch_bounds__(256)
void attn_fwd(const unsigned short* __restrict__ Qg,
              const unsigned short* __restrict__ Kg,
              const unsigned short* __restrict__ Vtg,
              unsigned short* __restrict__ Og) {
  // XCD-aware decode: 4 bh per XCD (K/V panels stay in one L2), qt descending
  int bid = blockIdx.x;            // 0..511
  int xcd = bid & 7, idx = bid >> 3;
  int bh  = xcd * 4 + (idx >> 4);  // 0..31
  int qt  = 15 - (idx & 15);       // 0..15, heavy first
  const int bb = bh >> 4, hh = bh & 15;
  const int tid = threadIdx.x, wid = tid >> 6, lane = tid & 63;
  const int l15 = lane & 15, lg = lane >> 4;
  const int q0 = qt * 128;
  const int wq = wid * 32;
  const size_t baseQ = (size_t)bb * Sn * Dn + (size_t)hh * DKn;  // Q/K/O base
  const size_t baseV = (size_t)bh * DKn * Sn;                    // Vt base

  __shared__ unsigned short Ks[64 * 64];    // K tile  [key][d], swz granules
  __shared__ unsigned short Vts[64 * 64];   // Vt tile [d][key], swz granules
  __shared__ unsigned short Ps[4][32 * 72]; // per-wave P [q][key], pad 72

  // Q fragments (B-operand: col=q=l15, k = d = lg*8+r)
  bf16x8 qf[2][2];
#pragma unroll
  for (int qm = 0; qm < 2; ++qm)
#pragma unroll
    for (int kd = 0; kd < 2; ++kd)
      qf[qm][kd] = *(const bf16x8*)(Qg + baseQ +
                   (size_t)(q0 + wq + qm * 16 + l15) * Dn + kd * 32 + lg * 8);

  // O^T accumulators: oacc[qm][dn][j]: q = qm*16+l15, d = dn*16+lg*4+j
  f32x4 oacc[2][4] = {};
  float mrun[2] = {-1e30f, -1e30f};
  float lrun[2] = {0.f, 0.f};

  const int lrow  = lane >> 3;              // staging row-within-chunk 0..7
  const int sgran = (lane & 7) ^ lrow;      // pre-swizzled source granule
  const int swz   = l15 & 7;                // read-side XOR
  const int myrowhi = q0 + wq + 31;
  const int ktmax = qt * 2 + 1;

  for (int kt = 0; kt <= ktmax; ++kt) {
    const int k0 = kt << 6;

    // stage K [key][d] and Vt [d][key] (linear dest, swizzled source granule)
#pragma unroll
    for (int p = 0; p < 2; ++p) {
      int c = p * 4 + wid;                  // 0..7
      int r = c * 8 + lrow;
      gload_lds16(Kg + baseQ + (size_t)(k0 + r) * Dn + sgran * 8, &Ks[c * 512]);
    }
#pragma unroll
    for (int p = 0; p < 2; ++p) {
      int c = p * 4 + wid;
      int dr = c * 8 + lrow;
      gload_lds16(Vtg + baseV + (size_t)dr * Sn + k0 + sgran * 8, &Vts[c * 512]);
    }
    __syncthreads();

    if (k0 <= myrowhi) {
      // S^T = K * Q : sf[qm][kn][j]: key = kn*16+lg*4+j, q = qm*16+l15
      f32x4 sf[2][4] = {};
#pragma unroll
      for (int kn = 0; kn < 4; ++kn)
#pragma unroll
        for (int kd = 0; kd < 2; ++kd) {
          bf16x8 kf = *(const bf16x8*)(&Ks[(kn * 16 + l15) * 64 +
                                           (((kd * 4 + lg) ^ swz) * 8)]);
          sf[0][kn] = mfma16(kf, qf[0][kd], sf[0][kn]);
          sf[1][kn] = mfma16(kf, qf[1][kd], sf[1][kn]);
        }

      if (k0 + 63 > q0 + wq) {              // causal mask (diag-overlap tiles)
#pragma unroll
        for (int qm = 0; qm < 2; ++qm) {
          int qq = q0 + wq + qm * 16 + l15;
#pragma unroll
          for (int kn = 0; kn < 4; ++kn)
#pragma unroll
            for (int j = 0; j < 4; ++j) {
              int key = k0 + kn * 16 + lg * 4 + j;
              if (key > qq) sf[qm][kn][j] = -1e30f;
            }
        }
      }

      // lane-local softmax per qm (lane's q = qm*16+l15)
#pragma unroll
      for (int qm = 0; qm < 2; ++qm) {
        float t = sf[qm][0][0];
#pragma unroll
        for (int kn = 0; kn < 4; ++kn)
#pragma unroll
          for (int j = 0; j < 4; ++j) t = fmaxf(t, sf[qm][kn][j]);
        t = fmaxf(t, __shfl_xor(t, 16));
        t = fmaxf(t, __shfl_xor(t, 32));
        float mnew = fmaxf(mrun[qm], t);
        float corr = __expf(mrun[qm] - mnew);
        mrun[qm] = mnew;
        lrun[qm] *= corr;
#pragma unroll
        for (int dn = 0; dn < 4; ++dn) oacc[qm][dn] *= corr;

        float rs = 0.f;
#pragma unroll
        for (int kn = 0; kn < 4; ++kn) {
#pragma unroll
          for (int j = 0; j < 4; ++j) {
            float p = __expf(sf[qm][kn][j] - mnew);
            sf[qm][kn][j] = p;
            rs += p;
          }
          // packed b64 write: P[q=qm*16+l15][key = kn*16+lg*4 + 0..3]
          ushort4 pw;
          pw.x = f2bf(sf[qm][kn][0]); pw.y = f2bf(sf[qm][kn][1]);
          pw.z = f2bf(sf[qm][kn][2]); pw.w = f2bf(sf[qm][kn][3]);
          *(ushort4*)(&Ps[wid][(qm * 16 + l15) * 72 + kn * 16 + lg * 4]) = pw;
        }
        rs += __shfl_xor(rs, 16);
        rs += __shfl_xor(rs, 32);
        lrun[qm] += rs;
      }

      // O^T += Vt * P : A = Vt (row=d), B = P (col=q)
#pragma unroll
      for (int kk = 0; kk < 2; ++kk) {
        bf16x8 pf[2];
#pragma unroll
        for (int qm = 0; qm < 2; ++qm)
          pf[qm] = *(const bf16x8*)(&Ps[wid][(qm * 16 + l15) * 72 + kk * 32 + lg * 8]);
#pragma unroll
        for (int dn = 0; dn < 4; ++dn) {
          bf16x8 vf = *(const bf16x8*)(&Vts[(dn * 16 + l15) * 64 +
                                            (((kk * 4 + lg) ^ swz) * 8)]);
#pragma unroll
          for (int qm = 0; qm < 2; ++qm)
            oacc[qm][dn] = mfma16(vf, pf[qm], oacc[qm][dn]);
        }
      }
    }
    __syncthreads();
  }

  // epilogue: O[q][d] = oacc / lrun; lane q = qm*16+l15, d = dn*16+lg*4+j
#pragma unroll
  for (int qm = 0; qm < 2; ++qm) {
    float rinv = 1.0f / lrun[qm];
    int row = q0 + wq + qm * 16 + l15;
#pragma unroll
    for (int dn = 0; dn < 4; ++dn) {
      ushort4 ow;
      ow.x = f2bf(oacc[qm][dn][0] * rinv);
      ow.y = f2bf(oacc[qm][dn][1] * rinv);
      ow.z = f2bf(oacc[qm][dn][2] * rinv);
      ow.w = f2bf(oacc[qm][dn][3] * rinv);
      *(ushort4*)(Og + baseQ + (size_t)row * Dn + dn * 16 + lg * 4) = ow;
    }
  }
}

// ---------------------------------------------------------------------------
extern "C" void kernel_launch(void* const* d_in, const int* in_sizes, int n_in,
                              void* d_out, int out_size, void* d_ws, size_t ws_size,
                              hipStream_t stream) {
  const float* x  = (const float*)d_in[0];
  const float* Wq = (const float*)d_in[1];
  const float* Wk = (const float*)d_in[2];
  const float* Wv = (const float*)d_in[3];
  const float* Wo = (const float*)d_in[4];
  float* out = (float*)d_out;

  char* ws = (char*)d_ws;
  size_t off = 0;
  unsigned short* xb  = (unsigned short*)(ws + off); off += (size_t)Mrows * Dn * 2;
  unsigned short* wqb = (unsigned short*)(ws + off); off += (size_t)Dn * Dn * 2;
  unsigned short* wkb = (unsigned short*)(ws + off); off += (size_t)Dn * Dn * 2;
  unsigned short* wvb = (unsigned short*)(ws + off); off += (size_t)Dn * Dn * 2;
  unsigned short* wob = (unsigned short*)(ws + off); off += (size_t)Dn * Dn * 2;
  unsigned short* Qb  = (unsigned short*)(ws + off); off += (size_t)Mrows * Dn * 2;
  unsigned short* Kb  = (unsigned short*)(ws + off); off += (size_t)Mrows * Dn * 2;
  unsigned short* Vtb = (unsigned short*)(ws + off); off += (size_t)Mrows * Dn * 2;
  unsigned short* Ob  = (unsigned short*)(ws + off); off += (size_t)Mrows * Dn * 2;

  cvt_all<<<8192, 256, 0, stream>>>(x, Wq, Wk, Wv, Wo, xb, wqb, wkb, wvb, wob);
  gemm_qkv<<<dim3(Mrows / 128, Dn / 128, 3), 256, 0, stream>>>(xb, wqb, wkb, wvb, Qb, Kb, Vtb);
  attn_fwd<<<512, 256, 0, stream>>>(Qb, Kb, Vtb, Ob);
  gemm_out<<<dim3(Mrows / 128, Dn / 128), 256, 0, stream>>>(Ob, wob, out);
}

// Round 4
// 149.655 us; speedup vs baseline: 1.7028x; 1.1669x over previous
//
#include <hip/hip_runtime.h>
#include <hip/hip_bf16.h>

typedef __attribute__((ext_vector_type(4))) float f32x4;
typedef __attribute__((ext_vector_type(8))) short bf16x8;

// Problem constants (B=2, S=2048, D=1024, H=16, DK=64)
#define Bn 2
#define Sn 2048
#define Dn 1024
#define Hn 16
#define DKn 64
#define Mrows (Bn * Sn)   // 4096

__device__ __forceinline__ unsigned short f2bf(float f) {
  unsigned int x = __float_as_uint(f);
  x += 0x7fffu + ((x >> 16) & 1u);   // round-to-nearest-even
  return (unsigned short)(x >> 16);
}

__device__ __forceinline__ f32x4 mfma16(bf16x8 a, bf16x8 b, f32x4 c) {
  return __builtin_amdgcn_mfma_f32_16x16x32_bf16(a, b, c, 0, 0, 0);
}

__device__ __forceinline__ void gload_lds16(const unsigned short* g, unsigned short* l) {
  __builtin_amdgcn_global_load_lds(
      (const __attribute__((address_space(1))) void*)g,
      (__attribute__((address_space(3))) void*)l, 16, 0, 0);
}

// ---------------------------------------------------------------------------
// fused fp32 -> bf16 convert for x + 4 weights (one launch)
// region by i>>20: 0..3 = x (4M elems), 4..7 = Wq,Wk,Wv,Wo (1M each)
// ---------------------------------------------------------------------------
__global__ __launch_bounds__(256)
void cvt_all(const float* __restrict__ x,  const float* __restrict__ wq,
             const float* __restrict__ wk, const float* __restrict__ wv,
             const float* __restrict__ wo,
             unsigned short* __restrict__ xb,  unsigned short* __restrict__ wqb,
             unsigned short* __restrict__ wkb, unsigned short* __restrict__ wvb,
             unsigned short* __restrict__ wob) {
  int i = (blockIdx.x * 256 + threadIdx.x) * 4;
  const float* src; unsigned short* dst; int off;
  int r = i >> 20;
  if (r < 4)       { src = x;  dst = xb;  off = i; }
  else if (r == 4) { src = wq; dst = wqb; off = i & 1048575; }
  else if (r == 5) { src = wk; dst = wkb; off = i & 1048575; }
  else if (r == 6) { src = wv; dst = wvb; off = i & 1048575; }
  else             { src = wo; dst = wob; off = i & 1048575; }
  float4 v = *(const float4*)(src + off);
  ushort4 o;
  o.x = f2bf(v.x); o.y = f2bf(v.y); o.z = f2bf(v.z); o.w = f2bf(v.w);
  *(ushort4*)(dst + off) = o;
}

// ---------------------------------------------------------------------------
// GEMM: C[M,N] = A[M,K] * W[N,K]^T  (bf16 in, fp32 accum)
// 128x128 tile, BK=64, 4 waves.  LDS tiles passed in (shared across MODEs).
// XOR source-granule swizzle on staging, matching XOR on fragment reads
// (both-sides-or-neither, rule #21).
// MODE 0: bf16 row-major, scaled by 0.125 (Q, pre-scaled by 1/sqrt(dk))
// MODE 1: bf16 row-major (K)
// MODE 2: bf16 transposed-V layout Vt[b][h][d][s] (packed 8B stores)
// MODE 3: fp32 row-major (final output)
// ---------------------------------------------------------------------------
template<int MODE>
__device__ __forceinline__ void gemm_body(const unsigned short* __restrict__ A,
                                          const unsigned short* __restrict__ W,
                                          unsigned short* __restrict__ Cb,
                                          float* __restrict__ Cf,
                                          unsigned short* As,
                                          unsigned short* Bs) {
  const int K = Dn, N = Dn;
  const int tid  = threadIdx.x;
  const int wid  = tid >> 6;
  const int lane = tid & 63;
  const int l15  = lane & 15;
  const int lg   = lane >> 4;
  const int row0 = blockIdx.x * 128;
  const int col0 = blockIdx.y * 128;
  const int wr = (wid >> 1) * 64;
  const int wc = (wid & 1) * 64;

  f32x4 acc[4][4] = {};

  const int lrow  = lane >> 3;             // 0..7 within a 1KB chunk
  const int sgran = (lane & 7) ^ lrow;     // pre-swizzled source granule
  const int swz   = l15 & 7;               // read-side XOR (row&7 == l15&7)

  for (int kt = 0; kt < K; kt += 64) {
#pragma unroll
    for (int p = 0; p < 4; ++p) {
      int chunk = p * 4 + wid;                       // 0..15
      int r = chunk * 8 + lrow;
      gload_lds16(A + (size_t)(row0 + r) * K + kt + sgran * 8, &As[chunk * 512]);
    }
#pragma unroll
    for (int p = 0; p < 4; ++p) {
      int chunk = p * 4 + wid;
      int r = chunk * 8 + lrow;
      gload_lds16(W + (size_t)(col0 + r) * K + kt + sgran * 8, &Bs[chunk * 512]);
    }
    __syncthreads();

#pragma unroll
    for (int kk = 0; kk < 2; ++kk) {
      bf16x8 af[4], bfr[4];
#pragma unroll
      for (int m = 0; m < 4; ++m)
        af[m] = *(const bf16x8*)(&As[(wr + m * 16 + l15) * 64 +
                                     (((kk * 4 + lg) ^ swz) * 8)]);
#pragma unroll
      for (int n = 0; n < 4; ++n)
        bfr[n] = *(const bf16x8*)(&Bs[(wc + n * 16 + l15) * 64 +
                                      (((kk * 4 + lg) ^ swz) * 8)]);
#pragma unroll
      for (int m = 0; m < 4; ++m)
#pragma unroll
        for (int n = 0; n < 4; ++n)
          acc[m][n] = mfma16(af[m], bfr[n], acc[m][n]);
    }
    __syncthreads();
  }

  // Epilogue: C/D layout col = lane&15, row = (lane>>4)*4 + j  [m89 verified]
#pragma unroll
  for (int m = 0; m < 4; ++m)
#pragma unroll
    for (int n = 0; n < 4; ++n) {
      int r0 = row0 + wr + m * 16 + lg * 4;
      int c  = col0 + wc + n * 16 + l15;
      if (MODE == 2) {
        // V transposed: Vt[((b*H + h)*DK + d)][s], s = token & 2047
        int b = r0 >> 11, s = r0 & 2047;
        int h = c >> 6,  d = c & 63;
        ushort4 pw;
        pw.x = f2bf(acc[m][n][0]); pw.y = f2bf(acc[m][n][1]);
        pw.z = f2bf(acc[m][n][2]); pw.w = f2bf(acc[m][n][3]);
        *(ushort4*)(Cb + ((((size_t)b * Hn + h) * DKn + d) << 11) + s) = pw;
      } else {
#pragma unroll
        for (int j = 0; j < 4; ++j) {
          size_t idx = (size_t)(r0 + j) * N + c;
          float v = acc[m][n][j];
          if (MODE == 3)      Cf[idx] = v;
          else if (MODE == 0) Cb[idx] = f2bf(v * 0.125f);
          else                Cb[idx] = f2bf(v);
        }
      }
    }
}

__global__ __launch_bounds__(256)
void gemm_qkv(const unsigned short* __restrict__ A,
              const unsigned short* __restrict__ W0,
              const unsigned short* __restrict__ W1,
              const unsigned short* __restrict__ W2,
              unsigned short* __restrict__ C0,
              unsigned short* __restrict__ C1,
              unsigned short* __restrict__ C2) {
  __shared__ unsigned short As[128 * 64];
  __shared__ unsigned short Bs[128 * 64];
  if (blockIdx.z == 0)      gemm_body<0>(A, W0, C0, nullptr, As, Bs);
  else if (blockIdx.z == 1) gemm_body<1>(A, W1, C1, nullptr, As, Bs);
  else                      gemm_body<2>(A, W2, C2, nullptr, As, Bs);
}

__global__ __launch_bounds__(256)
void gemm_out(const unsigned short* __restrict__ A,
              const unsigned short* __restrict__ W,
              float* __restrict__ C) {
  __shared__ unsigned short As[128 * 64];
  __shared__ unsigned short Bs[128 * 64];
  gemm_body<3>(A, W, nullptr, C, As, Bs);
}

// ---------------------------------------------------------------------------
// Flash attention (causal), swapped-operand form.
// Q pre-scaled by 1/sqrt(dk).  Q/K row-major [token][D]; V pre-transposed
// Vt[b][h][d][s].  Block: 128 q rows of one (b,h); 4 waves x 32 rows.
// KV tile = 64.  S^T = mfma(K, Q): lane's q = qm*16 + (lane&15) -> softmax
// is lane-local (in-register tree + 2 shfl_xor).  PV as mfma(Vt, P) -> O^T
// fragments, also lane-local through the epilogue.  P round-trips through
// per-wave LDS with packed b64 writes.  K/Vt staged via global_load_lds with
// XOR source-granule swizzle (linear LDS dest, rule #21).
// ---------------------------------------------------------------------------
__global__ __launch_bounds__(256)
void attn_fwd(const unsigned short* __restrict__ Qg,
              const unsigned short* __restrict__ Kg,
              const unsigned short* __restrict__ Vtg,
              unsigned short* __restrict__ Og) {
  // XCD-aware decode: 4 bh per XCD (K/V panels stay in one L2), qt descending
  int bid = blockIdx.x;            // 0..511
  int xcd = bid & 7, idx = bid >> 3;
  int bh  = xcd * 4 + (idx >> 4);  // 0..31
  int qt  = 15 - (idx & 15);       // 0..15, heavy first
  const int bb = bh >> 4, hh = bh & 15;
  const int tid = threadIdx.x, wid = tid >> 6, lane = tid & 63;
  const int l15 = lane & 15, lg = lane >> 4;
  const int q0 = qt * 128;
  const int wq = wid * 32;
  const size_t baseQ = (size_t)bb * Sn * Dn + (size_t)hh * DKn;  // Q/K/O base
  const size_t baseV = (size_t)bh * DKn * Sn;                    // Vt base

  __shared__ unsigned short Ks[64 * 64];    // K tile  [key][d], swz granules
  __shared__ unsigned short Vts[64 * 64];   // Vt tile [d][key], swz granules
  __shared__ unsigned short Ps[4][32 * 72]; // per-wave P [q][key], pad 72

  // Q fragments (B-operand: col=q=l15, k = d = lg*8+r)
  bf16x8 qf[2][2];
#pragma unroll
  for (int qm = 0; qm < 2; ++qm)
#pragma unroll
    for (int kd = 0; kd < 2; ++kd)
      qf[qm][kd] = *(const bf16x8*)(Qg + baseQ +
                   (size_t)(q0 + wq + qm * 16 + l15) * Dn + kd * 32 + lg * 8);

  // O^T accumulators: oacc[qm][dn][j]: q = qm*16+l15, d = dn*16+lg*4+j
  f32x4 oacc[2][4] = {};
  float mrun[2] = {-1e30f, -1e30f};
  float lrun[2] = {0.f, 0.f};

  const int lrow  = lane >> 3;              // staging row-within-chunk 0..7
  const int sgran = (lane & 7) ^ lrow;      // pre-swizzled source granule
  const int swz   = l15 & 7;                // read-side XOR
  const int myrowhi = q0 + wq + 31;
  const int ktmax = qt * 2 + 1;

  for (int kt = 0; kt <= ktmax; ++kt) {
    const int k0 = kt << 6;

    // stage K [key][d] and Vt [d][key] (linear dest, swizzled source granule)
#pragma unroll
    for (int p = 0; p < 2; ++p) {
      int c = p * 4 + wid;                  // 0..7
      int r = c * 8 + lrow;
      gload_lds16(Kg + baseQ + (size_t)(k0 + r) * Dn + sgran * 8, &Ks[c * 512]);
    }
#pragma unroll
    for (int p = 0; p < 2; ++p) {
      int c = p * 4 + wid;
      int dr = c * 8 + lrow;
      gload_lds16(Vtg + baseV + (size_t)dr * Sn + k0 + sgran * 8, &Vts[c * 512]);
    }
    __syncthreads();

    if (k0 <= myrowhi) {
      // S^T = K * Q : sf[qm][kn][j]: key = kn*16+lg*4+j, q = qm*16+l15
      f32x4 sf[2][4] = {};
#pragma unroll
      for (int kn = 0; kn < 4; ++kn)
#pragma unroll
        for (int kd = 0; kd < 2; ++kd) {
          bf16x8 kf = *(const bf16x8*)(&Ks[(kn * 16 + l15) * 64 +
                                           (((kd * 4 + lg) ^ swz) * 8)]);
          sf[0][kn] = mfma16(kf, qf[0][kd], sf[0][kn]);
          sf[1][kn] = mfma16(kf, qf[1][kd], sf[1][kn]);
        }

      if (k0 + 63 > q0 + wq) {              // causal mask (diag-overlap tiles)
#pragma unroll
        for (int qm = 0; qm < 2; ++qm) {
          int qq = q0 + wq + qm * 16 + l15;
#pragma unroll
          for (int kn = 0; kn < 4; ++kn)
#pragma unroll
            for (int j = 0; j < 4; ++j) {
              int key = k0 + kn * 16 + lg * 4 + j;
              if (key > qq) sf[qm][kn][j] = -1e30f;
            }
        }
      }

      // lane-local softmax per qm (lane's q = qm*16+l15)
#pragma unroll
      for (int qm = 0; qm < 2; ++qm) {
        float t = sf[qm][0][0];
#pragma unroll
        for (int kn = 0; kn < 4; ++kn)
#pragma unroll
          for (int j = 0; j < 4; ++j) t = fmaxf(t, sf[qm][kn][j]);
        t = fmaxf(t, __shfl_xor(t, 16));
        t = fmaxf(t, __shfl_xor(t, 32));
        float mnew = fmaxf(mrun[qm], t);
        float corr = __expf(mrun[qm] - mnew);
        mrun[qm] = mnew;
        lrun[qm] *= corr;
#pragma unroll
        for (int dn = 0; dn < 4; ++dn) oacc[qm][dn] *= corr;

        float rs = 0.f;
#pragma unroll
        for (int kn = 0; kn < 4; ++kn) {
#pragma unroll
          for (int j = 0; j < 4; ++j) {
            float p = __expf(sf[qm][kn][j] - mnew);
            sf[qm][kn][j] = p;
            rs += p;
          }
          // packed b64 write: P[q=qm*16+l15][key = kn*16+lg*4 + 0..3]
          ushort4 pw;
          pw.x = f2bf(sf[qm][kn][0]); pw.y = f2bf(sf[qm][kn][1]);
          pw.z = f2bf(sf[qm][kn][2]); pw.w = f2bf(sf[qm][kn][3]);
          *(ushort4*)(&Ps[wid][(qm * 16 + l15) * 72 + kn * 16 + lg * 4]) = pw;
        }
        rs += __shfl_xor(rs, 16);
        rs += __shfl_xor(rs, 32);
        lrun[qm] += rs;
      }

      // O^T += Vt * P : A = Vt (row=d), B = P (col=q)
#pragma unroll
      for (int kk = 0; kk < 2; ++kk) {
        bf16x8 pf[2];
#pragma unroll
        for (int qm = 0; qm < 2; ++qm)
          pf[qm] = *(const bf16x8*)(&Ps[wid][(qm * 16 + l15) * 72 + kk * 32 + lg * 8]);
#pragma unroll
        for (int dn = 0; dn < 4; ++dn) {
          bf16x8 vf = *(const bf16x8*)(&Vts[(dn * 16 + l15) * 64 +
                                            (((kk * 4 + lg) ^ swz) * 8)]);
#pragma unroll
          for (int qm = 0; qm < 2; ++qm)
            oacc[qm][dn] = mfma16(vf, pf[qm], oacc[qm][dn]);
        }
      }
    }
    __syncthreads();
  }

  // epilogue: O[q][d] = oacc / lrun; lane q = qm*16+l15, d = dn*16+lg*4+j
#pragma unroll
  for (int qm = 0; qm < 2; ++qm) {
    float rinv = 1.0f / lrun[qm];
    int row = q0 + wq + qm * 16 + l15;
#pragma unroll
    for (int dn = 0; dn < 4; ++dn) {
      ushort4 ow;
      ow.x = f2bf(oacc[qm][dn][0] * rinv);
      ow.y = f2bf(oacc[qm][dn][1] * rinv);
      ow.z = f2bf(oacc[qm][dn][2] * rinv);
      ow.w = f2bf(oacc[qm][dn][3] * rinv);
      *(ushort4*)(Og + baseQ + (size_t)row * Dn + dn * 16 + lg * 4) = ow;
    }
  }
}

// ---------------------------------------------------------------------------
extern "C" void kernel_launch(void* const* d_in, const int* in_sizes, int n_in,
                              void* d_out, int out_size, void* d_ws, size_t ws_size,
                              hipStream_t stream) {
  const float* x  = (const float*)d_in[0];
  const float* Wq = (const float*)d_in[1];
  const float* Wk = (const float*)d_in[2];
  const float* Wv = (const float*)d_in[3];
  const float* Wo = (const float*)d_in[4];
  float* out = (float*)d_out;

  char* ws = (char*)d_ws;
  size_t off = 0;
  unsigned short* xb  = (unsigned short*)(ws + off); off += (size_t)Mrows * Dn * 2;
  unsigned short* wqb = (unsigned short*)(ws + off); off += (size_t)Dn * Dn * 2;
  unsigned short* wkb = (unsigned short*)(ws + off); off += (size_t)Dn * Dn * 2;
  unsigned short* wvb = (unsigned short*)(ws + off); off += (size_t)Dn * Dn * 2;
  unsigned short* wob = (unsigned short*)(ws + off); off += (size_t)Dn * Dn * 2;
  unsigned short* Qb  = (unsigned short*)(ws + off); off += (size_t)Mrows * Dn * 2;
  unsigned short* Kb  = (unsigned short*)(ws + off); off += (size_t)Mrows * Dn * 2;
  unsigned short* Vtb = (unsigned short*)(ws + off); off += (size_t)Mrows * Dn * 2;
  unsigned short* Ob  = (unsigned short*)(ws + off); off += (size_t)Mrows * Dn * 2;

  cvt_all<<<8192, 256, 0, stream>>>(x, Wq, Wk, Wv, Wo, xb, wqb, wkb, wvb, wob);
  gemm_qkv<<<dim3(Mrows / 128, Dn / 128, 3), 256, 0, stream>>>(xb, wqb, wkb, wvb, Qb, Kb, Vtb);
  attn_fwd<<<512, 256, 0, stream>>>(Qb, Kb, Vtb, Ob);
  gemm_out<<<dim3(Mrows / 128, Dn / 128), 256, 0, stream>>>(Ob, wob, out);
}

// Round 5
// 137.243 us; speedup vs baseline: 1.8568x; 1.0904x over previous
//
#include <hip/hip_runtime.h>
#include <hip/hip_bf16.h>

typedef __attribute__((ext_vector_type(4))) float f32x4;
typedef __attribute__((ext_vector_type(8))) short bf16x8;

// Problem constants (B=2, S=2048, D=1024, H=16, DK=64)
#define Bn 2
#define Sn 2048
#define Dn 1024
#define Hn 16
#define DKn 64
#define Mrows (Bn * Sn)   // 4096

__device__ __forceinline__ unsigned short f2bf(float f) {
  unsigned int x = __float_as_uint(f);
  x += 0x7fffu + ((x >> 16) & 1u);   // round-to-nearest-even
  return (unsigned short)(x >> 16);
}

__device__ __forceinline__ unsigned int cvtpk(float lo, float hi) {
  unsigned int r;
  asm("v_cvt_pk_bf16_f32 %0, %1, %2" : "=v"(r) : "v"(lo), "v"(hi));
  return r;
}

__device__ __forceinline__ f32x4 mfma16(bf16x8 a, bf16x8 b, f32x4 c) {
  return __builtin_amdgcn_mfma_f32_16x16x32_bf16(a, b, c, 0, 0, 0);
}

__device__ __forceinline__ void gload_lds16(const unsigned short* g, unsigned short* l) {
  __builtin_amdgcn_global_load_lds(
      (const __attribute__((address_space(1))) void*)g,
      (__attribute__((address_space(3))) void*)l, 16, 0, 0);
}

// ---------------------------------------------------------------------------
// fused fp32 -> bf16 convert for x + 4 weights (one launch)
// ---------------------------------------------------------------------------
__global__ __launch_bounds__(256)
void cvt_all(const float* __restrict__ x,  const float* __restrict__ wq,
             const float* __restrict__ wk, const float* __restrict__ wv,
             const float* __restrict__ wo,
             unsigned short* __restrict__ xb,  unsigned short* __restrict__ wqb,
             unsigned short* __restrict__ wkb, unsigned short* __restrict__ wvb,
             unsigned short* __restrict__ wob) {
  int i = (blockIdx.x * 256 + threadIdx.x) * 4;
  const float* src; unsigned short* dst; int off;
  int r = i >> 20;
  if (r < 4)       { src = x;  dst = xb;  off = i; }
  else if (r == 4) { src = wq; dst = wqb; off = i & 1048575; }
  else if (r == 5) { src = wk; dst = wkb; off = i & 1048575; }
  else if (r == 6) { src = wv; dst = wvb; off = i & 1048575; }
  else             { src = wo; dst = wob; off = i & 1048575; }
  float4 v = *(const float4*)(src + off);
  ushort4 o;
  o.x = f2bf(v.x); o.y = f2bf(v.y); o.z = f2bf(v.z); o.w = f2bf(v.w);
  *(ushort4*)(dst + off) = o;
}

// ---------------------------------------------------------------------------
// GEMM: C[M,N] = A[M,K] * W[N,K]^T  (bf16 in, fp32 accum)
// 128x128 tile, BK=64, 4 waves.  XOR source-granule swizzle both sides.
// MODE 0: bf16, scaled 0.125 (Q) | 1: bf16 (K) | 2: Vt[b][h][d][s] | 3: fp32
// ---------------------------------------------------------------------------
template<int MODE>
__device__ __forceinline__ void gemm_body(const unsigned short* __restrict__ A,
                                          const unsigned short* __restrict__ W,
                                          unsigned short* __restrict__ Cb,
                                          float* __restrict__ Cf,
                                          unsigned short* As,
                                          unsigned short* Bs) {
  const int K = Dn, N = Dn;
  const int tid  = threadIdx.x;
  const int wid  = tid >> 6;
  const int lane = tid & 63;
  const int l15  = lane & 15;
  const int lg   = lane >> 4;
  const int row0 = blockIdx.x * 128;
  const int col0 = blockIdx.y * 128;
  const int wr = (wid >> 1) * 64;
  const int wc = (wid & 1) * 64;

  f32x4 acc[4][4] = {};

  const int lrow  = lane >> 3;
  const int sgran = (lane & 7) ^ lrow;
  const int swz   = l15 & 7;

  for (int kt = 0; kt < K; kt += 64) {
#pragma unroll
    for (int p = 0; p < 4; ++p) {
      int chunk = p * 4 + wid;
      int r = chunk * 8 + lrow;
      gload_lds16(A + (size_t)(row0 + r) * K + kt + sgran * 8, &As[chunk * 512]);
    }
#pragma unroll
    for (int p = 0; p < 4; ++p) {
      int chunk = p * 4 + wid;
      int r = chunk * 8 + lrow;
      gload_lds16(W + (size_t)(col0 + r) * K + kt + sgran * 8, &Bs[chunk * 512]);
    }
    __syncthreads();

#pragma unroll
    for (int kk = 0; kk < 2; ++kk) {
      bf16x8 af[4], bfr[4];
#pragma unroll
      for (int m = 0; m < 4; ++m)
        af[m] = *(const bf16x8*)(&As[(wr + m * 16 + l15) * 64 +
                                     (((kk * 4 + lg) ^ swz) * 8)]);
#pragma unroll
      for (int n = 0; n < 4; ++n)
        bfr[n] = *(const bf16x8*)(&Bs[(wc + n * 16 + l15) * 64 +
                                      (((kk * 4 + lg) ^ swz) * 8)]);
#pragma unroll
      for (int m = 0; m < 4; ++m)
#pragma unroll
        for (int n = 0; n < 4; ++n)
          acc[m][n] = mfma16(af[m], bfr[n], acc[m][n]);
    }
    __syncthreads();
  }

#pragma unroll
  for (int m = 0; m < 4; ++m)
#pragma unroll
    for (int n = 0; n < 4; ++n) {
      int r0 = row0 + wr + m * 16 + lg * 4;
      int c  = col0 + wc + n * 16 + l15;
      if (MODE == 2) {
        int b = r0 >> 11, s = r0 & 2047;
        int h = c >> 6,  d = c & 63;
        ushort4 pw;
        pw.x = f2bf(acc[m][n][0]); pw.y = f2bf(acc[m][n][1]);
        pw.z = f2bf(acc[m][n][2]); pw.w = f2bf(acc[m][n][3]);
        *(ushort4*)(Cb + ((((size_t)b * Hn + h) * DKn + d) << 11) + s) = pw;
      } else {
#pragma unroll
        for (int j = 0; j < 4; ++j) {
          size_t idx = (size_t)(r0 + j) * N + c;
          float v = acc[m][n][j];
          if (MODE == 3)      Cf[idx] = v;
          else if (MODE == 0) Cb[idx] = f2bf(v * 0.125f);
          else                Cb[idx] = f2bf(v);
        }
      }
    }
}

__global__ __launch_bounds__(256)
void gemm_qkv(const unsigned short* __restrict__ A,
              const unsigned short* __restrict__ W0,
              const unsigned short* __restrict__ W1,
              const unsigned short* __restrict__ W2,
              unsigned short* __restrict__ C0,
              unsigned short* __restrict__ C1,
              unsigned short* __restrict__ C2) {
  __shared__ unsigned short As[128 * 64];
  __shared__ unsigned short Bs[128 * 64];
  if (blockIdx.z == 0)      gemm_body<0>(A, W0, C0, nullptr, As, Bs);
  else if (blockIdx.z == 1) gemm_body<1>(A, W1, C1, nullptr, As, Bs);
  else                      gemm_body<2>(A, W2, C2, nullptr, As, Bs);
}

__global__ __launch_bounds__(256)
void gemm_out(const unsigned short* __restrict__ A,
              const unsigned short* __restrict__ W,
              float* __restrict__ C) {
  __shared__ unsigned short As[128 * 64];
  __shared__ unsigned short Bs[128 * 64];
  gemm_body<3>(A, W, nullptr, C, As, Bs);
}

// ---------------------------------------------------------------------------
// Flash attention (causal), swapped-operand form, double-buffered staging.
// Q pre-scaled by 1/sqrt(dk).  Q/K row-major; V pre-transposed Vt[b][h][d][s].
// Block: 128 q rows of one (b,h); 4 waves x 32 rows.  KV tile = 64.
// Complementary static pairing: bid and bid+256 land on the same CU
// (bid%8=XCD round-robin mapping) and get qt summing to 15 -> every CU
// pair does exactly 34 tile-iterations.  Stage(t+1) issued BEFORE
// compute(t) (T3 minimum 2-phase): barrier drain completes instantly.
// ---------------------------------------------------------------------------
__global__ __launch_bounds__(256)
void attn_fwd(const unsigned short* __restrict__ Qg,
              const unsigned short* __restrict__ Kg,
              const unsigned short* __restrict__ Vtg,
              unsigned short* __restrict__ Og) {
  const int bid = blockIdx.x;      // 0..511
  const int qt  = (bid < 256) ? (8 + (bid >> 5)) : (7 - ((bid - 256) >> 5));
  const int bh  = bid & 31;        // bh%8 == bid%8 -> 4 bh per XCD
  const int bb = bh >> 4, hh = bh & 15;
  const int tid = threadIdx.x, wid = tid >> 6, lane = tid & 63;
  const int l15 = lane & 15, lg = lane >> 4;
  const int q0 = qt * 128;
  const int wq = wid * 32;
  const size_t baseQ = (size_t)bb * Sn * Dn + (size_t)hh * DKn;  // Q/K/O base
  const size_t baseV = (size_t)bh * DKn * Sn;                    // Vt base

  __shared__ unsigned short Ks[2][64 * 64];   // K tile  [key][d], dbuf
  __shared__ unsigned short Vts[2][64 * 64];  // Vt tile [d][key], dbuf
  __shared__ unsigned short Ps[4][32 * 72];   // per-wave P [q][key], pad 72

  // Q fragments (B-operand: col=q=l15, k = d = lg*8+r)
  bf16x8 qf[2][2];
#pragma unroll
  for (int qm = 0; qm < 2; ++qm)
#pragma unroll
    for (int kd = 0; kd < 2; ++kd)
      qf[qm][kd] = *(const bf16x8*)(Qg + baseQ +
                   (size_t)(q0 + wq + qm * 16 + l15) * Dn + kd * 32 + lg * 8);

  f32x4 oacc[2][4] = {};
  float mrun[2] = {-1e30f, -1e30f};
  float lrun[2] = {0.f, 0.f};

  const int lrow  = lane >> 3;
  const int sgran = (lane & 7) ^ lrow;
  const int swz   = l15 & 7;
  const int myrowhi = q0 + wq + 31;
  const int ktmax = qt * 2 + 1;

  auto stage = [&](int kt, int b) {
    const int k0 = kt << 6;
#pragma unroll
    for (int p = 0; p < 2; ++p) {
      int c = p * 4 + wid;                  // 0..7
      int r = c * 8 + lrow;
      gload_lds16(Kg + baseQ + (size_t)(k0 + r) * Dn + sgran * 8, &Ks[b][c * 512]);
    }
#pragma unroll
    for (int p = 0; p < 2; ++p) {
      int c = p * 4 + wid;
      int dr = c * 8 + lrow;
      gload_lds16(Vtg + baseV + (size_t)dr * Sn + k0 + sgran * 8, &Vts[b][c * 512]);
    }
  };

  stage(0, 0);
  __syncthreads();

  for (int kt = 0; kt <= ktmax; ++kt) {
    const int cur = kt & 1;
    if (kt < ktmax) stage(kt + 1, cur ^ 1);   // prefetch next tile
    const int k0 = kt << 6;

    if (k0 <= myrowhi) {
      // S^T = K * Q : sf[qm][kn][j]: key = kn*16+lg*4+j, q = qm*16+l15
      f32x4 sf[2][4] = {};
      __builtin_amdgcn_s_setprio(1);
#pragma unroll
      for (int kn = 0; kn < 4; ++kn)
#pragma unroll
        for (int kd = 0; kd < 2; ++kd) {
          bf16x8 kf = *(const bf16x8*)(&Ks[cur][(kn * 16 + l15) * 64 +
                                              (((kd * 4 + lg) ^ swz) * 8)]);
          sf[0][kn] = mfma16(kf, qf[0][kd], sf[0][kn]);
          sf[1][kn] = mfma16(kf, qf[1][kd], sf[1][kn]);
        }
      __builtin_amdgcn_s_setprio(0);

      if (k0 + 63 > q0 + wq) {              // causal mask (diag-overlap tiles)
#pragma unroll
        for (int qm = 0; qm < 2; ++qm) {
          int qq = q0 + wq + qm * 16 + l15;
#pragma unroll
          for (int kn = 0; kn < 4; ++kn)
#pragma unroll
            for (int j = 0; j < 4; ++j) {
              int key = k0 + kn * 16 + lg * 4 + j;
              if (key > qq) sf[qm][kn][j] = -1e30f;
            }
        }
      }

      // lane-local softmax per qm (lane's q = qm*16+l15)
#pragma unroll
      for (int qm = 0; qm < 2; ++qm) {
        float t = sf[qm][0][0];
#pragma unroll
        for (int kn = 0; kn < 4; ++kn)
#pragma unroll
          for (int j = 0; j < 4; ++j) t = fmaxf(t, sf[qm][kn][j]);
        t = fmaxf(t, __shfl_xor(t, 16));
        t = fmaxf(t, __shfl_xor(t, 32));
        // defer-max: only rescale when some lane's max grew past THR=8
        if (__any(t > mrun[qm] + 8.0f)) {
          float mnew = fmaxf(mrun[qm], t);
          float corr = __expf(mrun[qm] - mnew);
          mrun[qm] = mnew;
          lrun[qm] *= corr;
#pragma unroll
          for (int dn = 0; dn < 4; ++dn) oacc[qm][dn] *= corr;
        }
        const float m = mrun[qm];
        float rs = 0.f;
#pragma unroll
        for (int kn = 0; kn < 4; ++kn) {
#pragma unroll
          for (int j = 0; j < 4; ++j) {
            float p = __expf(sf[qm][kn][j] - m);
            sf[qm][kn][j] = p;
            rs += p;
          }
          uint2 pw;
          pw.x = cvtpk(sf[qm][kn][0], sf[qm][kn][1]);
          pw.y = cvtpk(sf[qm][kn][2], sf[qm][kn][3]);
          *(uint2*)(&Ps[wid][(qm * 16 + l15) * 72 + kn * 16 + lg * 4]) = pw;
        }
        rs += __shfl_xor(rs, 16);
        rs += __shfl_xor(rs, 32);
        lrun[qm] += rs;
      }

      // O^T += Vt * P : A = Vt (row=d), B = P (col=q)
      __builtin_amdgcn_s_setprio(1);
#pragma unroll
      for (int kk = 0; kk < 2; ++kk) {
        bf16x8 pf[2];
#pragma unroll
        for (int qm = 0; qm < 2; ++qm)
          pf[qm] = *(const bf16x8*)(&Ps[wid][(qm * 16 + l15) * 72 + kk * 32 + lg * 8]);
#pragma unroll
        for (int dn = 0; dn < 4; ++dn) {
          bf16x8 vf = *(const bf16x8*)(&Vts[cur][(dn * 16 + l15) * 64 +
                                               (((kk * 4 + lg) ^ swz) * 8)]);
#pragma unroll
          for (int qm = 0; qm < 2; ++qm)
            oacc[qm][dn] = mfma16(vf, pf[qm], oacc[qm][dn]);
        }
      }
      __builtin_amdgcn_s_setprio(0);
    }
    __syncthreads();   // drains stage(t+1) vmcnt (latency already hidden)
  }

  // epilogue: O[q][d] = oacc / lrun
#pragma unroll
  for (int qm = 0; qm < 2; ++qm) {
    float rinv = 1.0f / lrun[qm];
    int row = q0 + wq + qm * 16 + l15;
#pragma unroll
    for (int dn = 0; dn < 4; ++dn) {
      ushort4 ow;
      ow.x = f2bf(oacc[qm][dn][0] * rinv);
      ow.y = f2bf(oacc[qm][dn][1] * rinv);
      ow.z = f2bf(oacc[qm][dn][2] * rinv);
      ow.w = f2bf(oacc[qm][dn][3] * rinv);
      *(ushort4*)(Og + baseQ + (size_t)row * Dn + dn * 16 + lg * 4) = ow;
    }
  }
}

// ---------------------------------------------------------------------------
extern "C" void kernel_launch(void* const* d_in, const int* in_sizes, int n_in,
                              void* d_out, int out_size, void* d_ws, size_t ws_size,
                              hipStream_t stream) {
  const float* x  = (const float*)d_in[0];
  const float* Wq = (const float*)d_in[1];
  const float* Wk = (const float*)d_in[2];
  const float* Wv = (const float*)d_in[3];
  const float* Wo = (const float*)d_in[4];
  float* out = (float*)d_out;

  char* ws = (char*)d_ws;
  size_t off = 0;
  unsigned short* xb  = (unsigned short*)(ws + off); off += (size_t)Mrows * Dn * 2;
  unsigned short* wqb = (unsigned short*)(ws + off); off += (size_t)Dn * Dn * 2;
  unsigned short* wkb = (unsigned short*)(ws + off); off += (size_t)Dn * Dn * 2;
  unsigned short* wvb = (unsigned short*)(ws + off); off += (size_t)Dn * Dn * 2;
  unsigned short* wob = (unsigned short*)(ws + off); off += (size_t)Dn * Dn * 2;
  unsigned short* Qb  = (unsigned short*)(ws + off); off += (size_t)Mrows * Dn * 2;
  unsigned short* Kb  = (unsigned short*)(ws + off); off += (size_t)Mrows * Dn * 2;
  unsigned short* Vtb = (unsigned short*)(ws + off); off += (size_t)Mrows * Dn * 2;
  unsigned short* Ob  = (unsigned short*)(ws + off); off += (size_t)Mrows * Dn * 2;

  cvt_all<<<8192, 256, 0, stream>>>(x, Wq, Wk, Wv, Wo, xb, wqb, wkb, wvb, wob);
  gemm_qkv<<<dim3(Mrows / 128, Dn / 128, 3), 256, 0, stream>>>(xb, wqb, wkb, wvb, Qb, Kb, Vtb);
  attn_fwd<<<512, 256, 0, stream>>>(Qb, Kb, Vtb, Ob);
  gemm_out<<<dim3(Mrows / 128, Dn / 128), 256, 0, stream>>>(Ob, wob, out);
}

// Round 6
// 126.514 us; speedup vs baseline: 2.0142x; 1.0848x over previous
//
#include <hip/hip_runtime.h>
#include <hip/hip_bf16.h>

typedef __attribute__((ext_vector_type(4))) float f32x4;
typedef __attribute__((ext_vector_type(8))) short bf16x8;

// Problem constants (B=2, S=2048, D=1024, H=16, DK=64)
#define Bn 2
#define Sn 2048
#define Dn 1024
#define Hn 16
#define DKn 64
#define Mrows (Bn * Sn)   // 4096

__device__ __forceinline__ unsigned short f2bf(float f) {
  unsigned int x = __float_as_uint(f);
  x += 0x7fffu + ((x >> 16) & 1u);   // round-to-nearest-even
  return (unsigned short)(x >> 16);
}

__device__ __forceinline__ float bf2f(unsigned short u) {
  return __uint_as_float(((unsigned int)u) << 16);
}

__device__ __forceinline__ unsigned int cvtpk(float lo, float hi) {
  unsigned int r;
  asm("v_cvt_pk_bf16_f32 %0, %1, %2" : "=v"(r) : "v"(lo), "v"(hi));
  return r;
}

__device__ __forceinline__ f32x4 mfma16(bf16x8 a, bf16x8 b, f32x4 c) {
  return __builtin_amdgcn_mfma_f32_16x16x32_bf16(a, b, c, 0, 0, 0);
}

__device__ __forceinline__ void gload_lds16(const unsigned short* g, unsigned short* l) {
  __builtin_amdgcn_global_load_lds(
      (const __attribute__((address_space(1))) void*)g,
      (__attribute__((address_space(3))) void*)l, 16, 0, 0);
}

// ---------------------------------------------------------------------------
// fused fp32 -> bf16 convert for x + 4 weights (one launch)
// ---------------------------------------------------------------------------
__global__ __launch_bounds__(256)
void cvt_all(const float* __restrict__ x,  const float* __restrict__ wq,
             const float* __restrict__ wk, const float* __restrict__ wv,
             const float* __restrict__ wo,
             unsigned short* __restrict__ xb,  unsigned short* __restrict__ wqb,
             unsigned short* __restrict__ wkb, unsigned short* __restrict__ wvb,
             unsigned short* __restrict__ wob) {
  int i = (blockIdx.x * 256 + threadIdx.x) * 4;
  const float* src; unsigned short* dst; int off;
  int r = i >> 20;
  if (r < 4)       { src = x;  dst = xb;  off = i; }
  else if (r == 4) { src = wq; dst = wqb; off = i & 1048575; }
  else if (r == 5) { src = wk; dst = wkb; off = i & 1048575; }
  else if (r == 6) { src = wv; dst = wvb; off = i & 1048575; }
  else             { src = wo; dst = wob; off = i & 1048575; }
  float4 v = *(const float4*)(src + off);
  ushort4 o;
  o.x = f2bf(v.x); o.y = f2bf(v.y); o.z = f2bf(v.z); o.w = f2bf(v.w);
  *(ushort4*)(dst + off) = o;
}

// ---------------------------------------------------------------------------
// GEMM: C[M,N] = A[M,K] * W[N,K]^T  (bf16 in, fp32 accum)
// 128x128 tile, BK=64, 4 waves.  XOR source-granule swizzle both sides.
// MODE 0: bf16, scaled 0.125 (Q) | 1: bf16 (K) | 2: Vt[b][h][d][s] | 3: fp32
// ---------------------------------------------------------------------------
template<int MODE>
__device__ __forceinline__ void gemm_body(const unsigned short* __restrict__ A,
                                          const unsigned short* __restrict__ W,
                                          unsigned short* __restrict__ Cb,
                                          float* __restrict__ Cf,
                                          unsigned short* As,
                                          unsigned short* Bs) {
  const int K = Dn, N = Dn;
  const int tid  = threadIdx.x;
  const int wid  = tid >> 6;
  const int lane = tid & 63;
  const int l15  = lane & 15;
  const int lg   = lane >> 4;
  const int row0 = blockIdx.x * 128;
  const int col0 = blockIdx.y * 128;
  const int wr = (wid >> 1) * 64;
  const int wc = (wid & 1) * 64;

  f32x4 acc[4][4] = {};

  const int lrow  = lane >> 3;
  const int sgran = (lane & 7) ^ lrow;
  const int swz   = l15 & 7;

  for (int kt = 0; kt < K; kt += 64) {
#pragma unroll
    for (int p = 0; p < 4; ++p) {
      int chunk = p * 4 + wid;
      int r = chunk * 8 + lrow;
      gload_lds16(A + (size_t)(row0 + r) * K + kt + sgran * 8, &As[chunk * 512]);
    }
#pragma unroll
    for (int p = 0; p < 4; ++p) {
      int chunk = p * 4 + wid;
      int r = chunk * 8 + lrow;
      gload_lds16(W + (size_t)(col0 + r) * K + kt + sgran * 8, &Bs[chunk * 512]);
    }
    __syncthreads();

#pragma unroll
    for (int kk = 0; kk < 2; ++kk) {
      bf16x8 af[4], bfr[4];
#pragma unroll
      for (int m = 0; m < 4; ++m)
        af[m] = *(const bf16x8*)(&As[(wr + m * 16 + l15) * 64 +
                                     (((kk * 4 + lg) ^ swz) * 8)]);
#pragma unroll
      for (int n = 0; n < 4; ++n)
        bfr[n] = *(const bf16x8*)(&Bs[(wc + n * 16 + l15) * 64 +
                                      (((kk * 4 + lg) ^ swz) * 8)]);
#pragma unroll
      for (int m = 0; m < 4; ++m)
#pragma unroll
        for (int n = 0; n < 4; ++n)
          acc[m][n] = mfma16(af[m], bfr[n], acc[m][n]);
    }
    __syncthreads();
  }

#pragma unroll
  for (int m = 0; m < 4; ++m)
#pragma unroll
    for (int n = 0; n < 4; ++n) {
      int r0 = row0 + wr + m * 16 + lg * 4;
      int c  = col0 + wc + n * 16 + l15;
      if (MODE == 2) {
        int b = r0 >> 11, s = r0 & 2047;
        int h = c >> 6,  d = c & 63;
        ushort4 pw;
        pw.x = f2bf(acc[m][n][0]); pw.y = f2bf(acc[m][n][1]);
        pw.z = f2bf(acc[m][n][2]); pw.w = f2bf(acc[m][n][3]);
        *(ushort4*)(Cb + ((((size_t)b * Hn + h) * DKn + d) << 11) + s) = pw;
      } else {
#pragma unroll
        for (int j = 0; j < 4; ++j) {
          size_t idx = (size_t)(r0 + j) * N + c;
          float v = acc[m][n][j];
          if (MODE == 3)      Cf[idx] = v;
          else if (MODE == 0) Cb[idx] = f2bf(v * 0.125f);
          else                Cb[idx] = f2bf(v);
        }
      }
    }
}

__global__ __launch_bounds__(256)
void gemm_qkv(const unsigned short* __restrict__ A,
              const unsigned short* __restrict__ W0,
              const unsigned short* __restrict__ W1,
              const unsigned short* __restrict__ W2,
              unsigned short* __restrict__ C0,
              unsigned short* __restrict__ C1,
              unsigned short* __restrict__ C2) {
  __shared__ unsigned short As[128 * 64];
  __shared__ unsigned short Bs[128 * 64];
  if (blockIdx.z == 0)      gemm_body<0>(A, W0, C0, nullptr, As, Bs);
  else if (blockIdx.z == 1) gemm_body<1>(A, W1, C1, nullptr, As, Bs);
  else                      gemm_body<2>(A, W2, C2, nullptr, As, Bs);
}

__global__ __launch_bounds__(256)
void gemm_out(const unsigned short* __restrict__ A,
              const unsigned short* __restrict__ W,
              float* __restrict__ C) {
  __shared__ unsigned short As[128 * 64];
  __shared__ unsigned short Bs[128 * 64];
  gemm_body<3>(A, W, nullptr, C, As, Bs);
}

// ---------------------------------------------------------------------------
// Flash attention (causal), swapped-operand form, UNIFORM KV-SPLIT.
// Work enumeration per bh: segments qt=0..15 at [qt(qt+1), qt(qt+1)+2qt+2)
// in a flat 272-tile space; 272 = 16*17 -> 512 blocks each own exactly 17
// consecutive KV tiles (perfect balance, 2 blocks/CU resident throughout).
// Whole segments finalize to Og; split segments write partials (bf16 O^T +
// fp32 m,l) at static slots; attn_combine merges them.
// ---------------------------------------------------------------------------
__global__ __launch_bounds__(256)
void attn_part(const unsigned short* __restrict__ Qg,
               const unsigned short* __restrict__ Kg,
               const unsigned short* __restrict__ Vtg,
               unsigned short* __restrict__ Og,
               unsigned short* __restrict__ Pb,
               float* __restrict__ Pml) {
  const int bid = blockIdx.x;      // 0..511
  const int bh = bid & 31;         // bh%8 -> XCD: each bh's KV on one L2
  const int j  = bid >> 5;         // 0..15: which 17-tile run
  const int bb = bh >> 4, hh = bh & 15;
  const int tid = threadIdx.x, wid = tid >> 6, lane = tid & 63;
  const int l15 = lane & 15, lg = lane >> 4;
  const int wq = wid * 32;
  const size_t baseQ = (size_t)bb * Sn * Dn + (size_t)hh * DKn;
  const size_t baseV = (size_t)bh * DKn * Sn;

  __shared__ unsigned short Ks[2][64 * 64];   // K tile  [key][d], dbuf
  __shared__ unsigned short Vts[2][64 * 64];  // Vt tile [d][key], dbuf
  __shared__ unsigned short Ps[4][32 * 72];   // per-wave P [q][key], pad 72

  const int lrow  = lane >> 3;
  const int sgran = (lane & 7) ^ lrow;
  const int swz   = l15 & 7;

  // locate starting segment
  const int g0 = 17 * j;
  int qt = 0;
  while ((qt + 1) * (qt + 2) <= g0) ++qt;
  int kt = g0 - qt * (qt + 1);     // kv-tile index within segment (= global kv tile)

  // staging pipeline (flat over the block's 17 tiles)
  int sqt = qt, skt = kt;
  auto stage = [&](int t, int b) {
    const int k0 = t << 6;
#pragma unroll
    for (int p = 0; p < 2; ++p) {
      int c = p * 4 + wid;
      int r = c * 8 + lrow;
      gload_lds16(Kg + baseQ + (size_t)(k0 + r) * Dn + sgran * 8, &Ks[b][c * 512]);
    }
#pragma unroll
    for (int p = 0; p < 2; ++p) {
      int c = p * 4 + wid;
      int dr = c * 8 + lrow;
      gload_lds16(Vtg + baseV + (size_t)dr * Sn + k0 + sgran * 8, &Vts[b][c * 512]);
    }
  };
  auto advs = [&]() { ++skt; if (skt == 2 * sqt + 2) { skt = 0; ++sqt; } };

  stage(skt, 0); advs();
  __syncthreads();

  bf16x8 qf[2][2];
  auto loadQ = [&](int qtile) {
    const int q0 = qtile * 128;
#pragma unroll
    for (int qm = 0; qm < 2; ++qm)
#pragma unroll
      for (int kd = 0; kd < 2; ++kd)
        qf[qm][kd] = *(const bf16x8*)(Qg + baseQ +
                     (size_t)(q0 + wq + qm * 16 + l15) * Dn + kd * 32 + lg * 8);
  };
  loadQ(qt);

  f32x4 oacc[2][4] = {};
  float mrun[2] = {-1e30f, -1e30f};
  float lrun[2] = {0.f, 0.f};
  int pstart = kt;                 // first kv-tile of current segment piece

  for (int i = 0; i < 17; ++i) {
    const int cur = i & 1;
    if (i < 16) { stage(skt, cur ^ 1); advs(); }
    const int k0 = kt << 6;
    const int q0 = qt * 128;

    if (k0 <= q0 + wq + 31) {      // wave-level causal skip
      f32x4 sf[2][4] = {};
      __builtin_amdgcn_s_setprio(1);
#pragma unroll
      for (int kn = 0; kn < 4; ++kn)
#pragma unroll
        for (int kd = 0; kd < 2; ++kd) {
          bf16x8 kf = *(const bf16x8*)(&Ks[cur][(kn * 16 + l15) * 64 +
                                              (((kd * 4 + lg) ^ swz) * 8)]);
          sf[0][kn] = mfma16(kf, qf[0][kd], sf[0][kn]);
          sf[1][kn] = mfma16(kf, qf[1][kd], sf[1][kn]);
        }
      __builtin_amdgcn_s_setprio(0);

      if (k0 + 63 > q0 + wq) {     // causal mask (diag-overlap tiles)
#pragma unroll
        for (int qm = 0; qm < 2; ++qm) {
          int qq = q0 + wq + qm * 16 + l15;
#pragma unroll
          for (int kn = 0; kn < 4; ++kn)
#pragma unroll
            for (int jj = 0; jj < 4; ++jj) {
              int key = k0 + kn * 16 + lg * 4 + jj;
              if (key > qq) sf[qm][kn][jj] = -1e30f;
            }
        }
      }

#pragma unroll
      for (int qm = 0; qm < 2; ++qm) {
        float t = sf[qm][0][0];
#pragma unroll
        for (int kn = 0; kn < 4; ++kn)
#pragma unroll
          for (int jj = 0; jj < 4; ++jj) t = fmaxf(t, sf[qm][kn][jj]);
        t = fmaxf(t, __shfl_xor(t, 16));
        t = fmaxf(t, __shfl_xor(t, 32));
        if (__any(t > mrun[qm] + 8.0f)) {       // defer-max THR=8
          float mnew = fmaxf(mrun[qm], t);
          float corr = __expf(mrun[qm] - mnew);
          mrun[qm] = mnew;
          lrun[qm] *= corr;
#pragma unroll
          for (int dn = 0; dn < 4; ++dn) oacc[qm][dn] *= corr;
        }
        const float m = mrun[qm];
        float rs = 0.f;
#pragma unroll
        for (int kn = 0; kn < 4; ++kn) {
#pragma unroll
          for (int jj = 0; jj < 4; ++jj) {
            float p = __expf(sf[qm][kn][jj] - m);
            sf[qm][kn][jj] = p;
            rs += p;
          }
          uint2 pw;
          pw.x = cvtpk(sf[qm][kn][0], sf[qm][kn][1]);
          pw.y = cvtpk(sf[qm][kn][2], sf[qm][kn][3]);
          *(uint2*)(&Ps[wid][(qm * 16 + l15) * 72 + kn * 16 + lg * 4]) = pw;
        }
        rs += __shfl_xor(rs, 16);
        rs += __shfl_xor(rs, 32);
        lrun[qm] += rs;
      }

      __builtin_amdgcn_s_setprio(1);
#pragma unroll
      for (int kk = 0; kk < 2; ++kk) {
        bf16x8 pf[2];
#pragma unroll
        for (int qm = 0; qm < 2; ++qm)
          pf[qm] = *(const bf16x8*)(&Ps[wid][(qm * 16 + l15) * 72 + kk * 32 + lg * 8]);
#pragma unroll
        for (int dn = 0; dn < 4; ++dn) {
          bf16x8 vf = *(const bf16x8*)(&Vts[cur][(dn * 16 + l15) * 64 +
                                               (((kk * 4 + lg) ^ swz) * 8)]);
#pragma unroll
          for (int qm = 0; qm < 2; ++qm)
            oacc[qm][dn] = mfma16(vf, pf[qm], oacc[qm][dn]);
        }
      }
      __builtin_amdgcn_s_setprio(0);
    }

    const bool segend = (kt == 2 * qt + 1);
    if (segend || i == 16) {
      if (pstart == 0 && segend) {
        // whole segment in this block: finalize to Og
#pragma unroll
        for (int qm = 0; qm < 2; ++qm) {
          float rinv = 1.0f / lrun[qm];
          int row = q0 + wq + qm * 16 + l15;
#pragma unroll
          for (int dn = 0; dn < 4; ++dn) {
            ushort4 ow;
            ow.x = f2bf(oacc[qm][dn][0] * rinv);
            ow.y = f2bf(oacc[qm][dn][1] * rinv);
            ow.z = f2bf(oacc[qm][dn][2] * rinv);
            ow.w = f2bf(oacc[qm][dn][3] * rinv);
            *(ushort4*)(Og + baseQ + (size_t)row * Dn + dn * 16 + lg * 4) = ow;
          }
        }
      } else {
        // partial: slot = ((bh*16+qt)*3 + ord)
        const int seg_s = qt * (qt + 1);
        const int ord = pstart ? ((seg_s + pstart) / 17 - seg_s / 17) : 0;
        const size_t slot = (size_t)((bh * 16 + qt) * 3 + ord);
#pragma unroll
        for (int qm = 0; qm < 2; ++qm) {
          int rl = wq + qm * 16 + l15;     // local row 0..127
#pragma unroll
          for (int dn = 0; dn < 4; ++dn) {
            ushort4 ow;
            ow.x = f2bf(oacc[qm][dn][0]);
            ow.y = f2bf(oacc[qm][dn][1]);
            ow.z = f2bf(oacc[qm][dn][2]);
            ow.w = f2bf(oacc[qm][dn][3]);
            *(ushort4*)(Pb + slot * 8192 + (size_t)rl * 64 + dn * 16 + lg * 4) = ow;
          }
          if (lg == 0) {
            Pml[slot * 256 + rl] = mrun[qm];
            Pml[slot * 256 + 128 + rl] = lrun[qm];
          }
        }
      }
      if (i < 16) {
        ++qt; kt = 0; pstart = 0;
        loadQ(qt);
#pragma unroll
        for (int qm = 0; qm < 2; ++qm) {
          mrun[qm] = -1e30f; lrun[qm] = 0.f;
#pragma unroll
          for (int dn = 0; dn < 4; ++dn) oacc[qm][dn] = f32x4{0.f, 0.f, 0.f, 0.f};
        }
      }
    } else {
      ++kt;
    }
    __syncthreads();
  }
}

// ---------------------------------------------------------------------------
// Merge partials for split segments.  One block per (bh,qt); exits fast for
// non-split segments (those were finalized in attn_part).
// ---------------------------------------------------------------------------
__global__ __launch_bounds__(256)
void attn_combine(const unsigned short* __restrict__ Pb,
                  const float* __restrict__ Pml,
                  unsigned short* __restrict__ Og) {
  const int b = blockIdx.x;        // bh*16 + qt
  const int bh = b >> 4, qt = b & 15;
  const int seg_s = qt * (qt + 1);
  const int seg_e = seg_s + 2 * qt + 2;
  const int c0 = (seg_s / 17 + 1) * 17;
  if (c0 >= seg_e) return;         // not split
  const int np = (c0 + 17 < seg_e) ? 3 : 2;
  const int bb = bh >> 4, hh = bh & 15;
  const size_t baseQ = (size_t)bb * Sn * Dn + (size_t)hh * DKn;
  const int q0 = qt * 128;
  const int slot0 = b * 3;
  const int r = threadIdx.x >> 1;          // 0..127
  const int c32 = (threadIdx.x & 1) * 32;  // col half

  float m0 = Pml[(size_t)slot0 * 256 + r];
  float l0 = Pml[(size_t)slot0 * 256 + 128 + r];
  float m1 = Pml[(size_t)(slot0 + 1) * 256 + r];
  float l1 = Pml[(size_t)(slot0 + 1) * 256 + 128 + r];
  float m2 = -1e30f, l2 = 0.f;
  if (np == 3) {
    m2 = Pml[(size_t)(slot0 + 2) * 256 + r];
    l2 = Pml[(size_t)(slot0 + 2) * 256 + 128 + r];
  }
  float M = fmaxf(fmaxf(m0, m1), m2);
  float w0 = __expf(m0 - M), w1 = __expf(m1 - M);
  float w2 = (np == 3) ? __expf(m2 - M) : 0.f;
  float L = l0 * w0 + l1 * w1 + l2 * w2;

  float acc[32];
#pragma unroll
  for (int k = 0; k < 32; ++k) acc[k] = 0.f;

  auto accum = [&](int p, float w) {
    const unsigned short* src = Pb + (size_t)(slot0 + p) * 8192 + (size_t)r * 64 + c32;
#pragma unroll
    for (int k4 = 0; k4 < 8; ++k4) {
      ushort4 v = *(const ushort4*)(src + k4 * 4);
      acc[k4 * 4 + 0] += w * bf2f(v.x);
      acc[k4 * 4 + 1] += w * bf2f(v.y);
      acc[k4 * 4 + 2] += w * bf2f(v.z);
      acc[k4 * 4 + 3] += w * bf2f(v.w);
    }
  };
  accum(0, w0);
  accum(1, w1);
  if (np == 3) accum(2, w2);

  float rinv = 1.0f / L;
#pragma unroll
  for (int k4 = 0; k4 < 8; ++k4) {
    ushort4 o;
    o.x = f2bf(acc[k4 * 4 + 0] * rinv);
    o.y = f2bf(acc[k4 * 4 + 1] * rinv);
    o.z = f2bf(acc[k4 * 4 + 2] * rinv);
    o.w = f2bf(acc[k4 * 4 + 3] * rinv);
    *(ushort4*)(Og + baseQ + (size_t)(q0 + r) * Dn + c32 + k4 * 4) = o;
  }
}

// ---------------------------------------------------------------------------
extern "C" void kernel_launch(void* const* d_in, const int* in_sizes, int n_in,
                              void* d_out, int out_size, void* d_ws, size_t ws_size,
                              hipStream_t stream) {
  const float* x  = (const float*)d_in[0];
  const float* Wq = (const float*)d_in[1];
  const float* Wk = (const float*)d_in[2];
  const float* Wv = (const float*)d_in[3];
  const float* Wo = (const float*)d_in[4];
  float* out = (float*)d_out;

  char* ws = (char*)d_ws;
  size_t off = 0;
  unsigned short* xb  = (unsigned short*)(ws + off); off += (size_t)Mrows * Dn * 2;
  unsigned short* wqb = (unsigned short*)(ws + off); off += (size_t)Dn * Dn * 2;
  unsigned short* wkb = (unsigned short*)(ws + off); off += (size_t)Dn * Dn * 2;
  unsigned short* wvb = (unsigned short*)(ws + off); off += (size_t)Dn * Dn * 2;
  unsigned short* wob = (unsigned short*)(ws + off); off += (size_t)Dn * Dn * 2;
  unsigned short* Qb  = (unsigned short*)(ws + off); off += (size_t)Mrows * Dn * 2;
  unsigned short* Kb  = (unsigned short*)(ws + off); off += (size_t)Mrows * Dn * 2;
  unsigned short* Vtb = (unsigned short*)(ws + off); off += (size_t)Mrows * Dn * 2;
  unsigned short* Ob  = (unsigned short*)(ws + off); off += (size_t)Mrows * Dn * 2;
  unsigned short* Pb  = (unsigned short*)(ws + off); off += (size_t)512 * 3 * 8192 * 2;
  float*          Pml = (float*)(ws + off);          off += (size_t)512 * 3 * 256 * 4;

  cvt_all<<<8192, 256, 0, stream>>>(x, Wq, Wk, Wv, Wo, xb, wqb, wkb, wvb, wob);
  gemm_qkv<<<dim3(Mrows / 128, Dn / 128, 3), 256, 0, stream>>>(xb, wqb, wkb, wvb, Qb, Kb, Vtb);
  attn_part<<<512, 256, 0, stream>>>(Qb, Kb, Vtb, Ob, Pb, Pml);
  attn_combine<<<512, 256, 0, stream>>>(Pb, Pml, Ob);
  gemm_out<<<dim3(Mrows / 128, Dn / 128), 256, 0, stream>>>(Ob, wob, out);
}

// Round 7
// 118.197 us; speedup vs baseline: 2.1560x; 1.0704x over previous
//
#include <hip/hip_runtime.h>
#include <hip/hip_bf16.h>

typedef __attribute__((ext_vector_type(4))) float f32x4;
typedef __attribute__((ext_vector_type(8))) short bf16x8;

// Problem constants (B=2, S=2048, D=1024, H=16, DK=64)
#define Bn 2
#define Sn 2048
#define Dn 1024
#define Hn 16
#define DKn 64
#define Mrows (Bn * Sn)   // 4096

__device__ __forceinline__ unsigned short f2bf(float f) {
  unsigned int x = __float_as_uint(f);
  x += 0x7fffu + ((x >> 16) & 1u);   // round-to-nearest-even
  return (unsigned short)(x >> 16);
}

__device__ __forceinline__ float bf2f(unsigned short u) {
  return __uint_as_float(((unsigned int)u) << 16);
}

__device__ __forceinline__ unsigned int cvtpk(float lo, float hi) {
  unsigned int r;
  asm("v_cvt_pk_bf16_f32 %0, %1, %2" : "=v"(r) : "v"(lo), "v"(hi));
  return r;
}

__device__ __forceinline__ f32x4 mfma16(bf16x8 a, bf16x8 b, f32x4 c) {
  return __builtin_amdgcn_mfma_f32_16x16x32_bf16(a, b, c, 0, 0, 0);
}

__device__ __forceinline__ void gload_lds16(const unsigned short* g, unsigned short* l) {
  __builtin_amdgcn_global_load_lds(
      (const __attribute__((address_space(1))) void*)g,
      (__attribute__((address_space(3))) void*)l, 16, 0, 0);
}

// ---------------------------------------------------------------------------
// fused fp32 -> bf16 convert for x + 4 weights (one launch)
// ---------------------------------------------------------------------------
__global__ __launch_bounds__(256)
void cvt_all(const float* __restrict__ x,  const float* __restrict__ wq,
             const float* __restrict__ wk, const float* __restrict__ wv,
             const float* __restrict__ wo,
             unsigned short* __restrict__ xb,  unsigned short* __restrict__ wqb,
             unsigned short* __restrict__ wkb, unsigned short* __restrict__ wvb,
             unsigned short* __restrict__ wob) {
  int i = (blockIdx.x * 256 + threadIdx.x) * 4;
  const float* src; unsigned short* dst; int off;
  int r = i >> 20;
  if (r < 4)       { src = x;  dst = xb;  off = i; }
  else if (r == 4) { src = wq; dst = wqb; off = i & 1048575; }
  else if (r == 5) { src = wk; dst = wkb; off = i & 1048575; }
  else if (r == 6) { src = wv; dst = wvb; off = i & 1048575; }
  else             { src = wo; dst = wob; off = i & 1048575; }
  float4 v = *(const float4*)(src + off);
  ushort4 o;
  o.x = f2bf(v.x); o.y = f2bf(v.y); o.z = f2bf(v.z); o.w = f2bf(v.w);
  *(ushort4*)(dst + off) = o;
}

// ---------------------------------------------------------------------------
// GEMM: C[M,N] = A[M,K] * W[N,K]^T  (bf16 in, fp32 accum)
// 128x128 tile, BK=64, 4 waves.  XOR source-granule swizzle both sides.
// 2-deep counted-vmcnt pipeline (T4): double-buffered LDS, prologue keeps
// 16 loads in flight; per-K-step s_waitcnt vmcnt(8) + raw s_barrier (never
// a full drain in the main loop).  Tail drains 8 -> 0.
// MODE 0: bf16, scaled 0.125 (Q) | 1: bf16 (K) | 2: Vt[b][h][d][s] | 3: fp32
// ---------------------------------------------------------------------------
template<int MODE>
__device__ __forceinline__ void gemm_body(const unsigned short* __restrict__ A,
                                          const unsigned short* __restrict__ W,
                                          unsigned short* __restrict__ Cb,
                                          float* __restrict__ Cf,
                                          unsigned short* As,   // [2][128*64]
                                          unsigned short* Bs) { // [2][128*64]
  const int K = Dn, N = Dn;
  const int tid  = threadIdx.x;
  const int wid  = tid >> 6;
  const int lane = tid & 63;
  const int l15  = lane & 15;
  const int lg   = lane >> 4;
  const int row0 = blockIdx.x * 128;
  const int col0 = blockIdx.y * 128;
  const int wr = (wid >> 1) * 64;
  const int wc = (wid & 1) * 64;

  f32x4 acc[4][4] = {};

  const int lrow  = lane >> 3;
  const int sgran = (lane & 7) ^ lrow;
  const int swz   = l15 & 7;

  auto stage = [&](int kt, int b) {
#pragma unroll
    for (int p = 0; p < 4; ++p) {
      int chunk = p * 4 + wid;
      int r = chunk * 8 + lrow;
      gload_lds16(A + (size_t)(row0 + r) * K + kt + sgran * 8,
                  &As[b * 8192 + chunk * 512]);
    }
#pragma unroll
    for (int p = 0; p < 4; ++p) {
      int chunk = p * 4 + wid;
      int r = chunk * 8 + lrow;
      gload_lds16(W + (size_t)(col0 + r) * K + kt + sgran * 8,
                  &Bs[b * 8192 + chunk * 512]);
    }
  };

  auto compute = [&](int b) {
#pragma unroll
    for (int kk = 0; kk < 2; ++kk) {
      bf16x8 af[4], bfr[4];
#pragma unroll
      for (int m = 0; m < 4; ++m)
        af[m] = *(const bf16x8*)(&As[b * 8192 + (wr + m * 16 + l15) * 64 +
                                     (((kk * 4 + lg) ^ swz) * 8)]);
#pragma unroll
      for (int n = 0; n < 4; ++n)
        bfr[n] = *(const bf16x8*)(&Bs[b * 8192 + (wc + n * 16 + l15) * 64 +
                                      (((kk * 4 + lg) ^ swz) * 8)]);
      __builtin_amdgcn_s_setprio(1);
#pragma unroll
      for (int m = 0; m < 4; ++m)
#pragma unroll
        for (int n = 0; n < 4; ++n)
          acc[m][n] = mfma16(af[m], bfr[n], acc[m][n]);
      __builtin_amdgcn_s_setprio(0);
    }
  };

  stage(0, 0);
  stage(64, 1);
  // main loop: K/64 = 16 steps; steady state 16 loads in flight
#pragma unroll 1
  for (int kt = 0; kt < 14; ++kt) {
    asm volatile("s_waitcnt vmcnt(8)" ::: "memory");
    __builtin_amdgcn_sched_barrier(0);
    __builtin_amdgcn_s_barrier();
    compute(kt & 1);
    __builtin_amdgcn_sched_barrier(0);
    __builtin_amdgcn_s_barrier();
    stage((kt + 2) * 64, kt & 1);
  }
  asm volatile("s_waitcnt vmcnt(8)" ::: "memory");
  __builtin_amdgcn_sched_barrier(0);
  __builtin_amdgcn_s_barrier();
  compute(0);
  asm volatile("s_waitcnt vmcnt(0)" ::: "memory");
  __builtin_amdgcn_sched_barrier(0);
  __builtin_amdgcn_s_barrier();
  compute(1);

#pragma unroll
  for (int m = 0; m < 4; ++m)
#pragma unroll
    for (int n = 0; n < 4; ++n) {
      int r0 = row0 + wr + m * 16 + lg * 4;
      int c  = col0 + wc + n * 16 + l15;
      if (MODE == 2) {
        int b = r0 >> 11, s = r0 & 2047;
        int h = c >> 6,  d = c & 63;
        ushort4 pw;
        pw.x = f2bf(acc[m][n][0]); pw.y = f2bf(acc[m][n][1]);
        pw.z = f2bf(acc[m][n][2]); pw.w = f2bf(acc[m][n][3]);
        *(ushort4*)(Cb + ((((size_t)b * Hn + h) * DKn + d) << 11) + s) = pw;
      } else {
#pragma unroll
        for (int j = 0; j < 4; ++j) {
          size_t idx = (size_t)(r0 + j) * N + c;
          float v = acc[m][n][j];
          if (MODE == 3)      Cf[idx] = v;
          else if (MODE == 0) Cb[idx] = f2bf(v * 0.125f);
          else                Cb[idx] = f2bf(v);
        }
      }
    }
}

__global__ __launch_bounds__(256)
void gemm_qkv(const unsigned short* __restrict__ A,
              const unsigned short* __restrict__ W0,
              const unsigned short* __restrict__ W1,
              const unsigned short* __restrict__ W2,
              unsigned short* __restrict__ C0,
              unsigned short* __restrict__ C1,
              unsigned short* __restrict__ C2) {
  __shared__ unsigned short As[2 * 128 * 64];
  __shared__ unsigned short Bs[2 * 128 * 64];
  if (blockIdx.z == 0)      gemm_body<0>(A, W0, C0, nullptr, As, Bs);
  else if (blockIdx.z == 1) gemm_body<1>(A, W1, C1, nullptr, As, Bs);
  else                      gemm_body<2>(A, W2, C2, nullptr, As, Bs);
}

__global__ __launch_bounds__(256)
void gemm_out(const unsigned short* __restrict__ A,
              const unsigned short* __restrict__ W,
              float* __restrict__ C) {
  __shared__ unsigned short As[2 * 128 * 64];
  __shared__ unsigned short Bs[2 * 128 * 64];
  gemm_body<3>(A, W, nullptr, C, As, Bs);
}

// ---------------------------------------------------------------------------
// Flash attention (causal), swapped-operand form, UNIFORM KV-SPLIT.
// 512 blocks x exactly 17 KV tiles (272 = 16*17 per bh); whole segments
// finalize to Og, split segments write partials merged by attn_combine.
// ---------------------------------------------------------------------------
__global__ __launch_bounds__(256)
void attn_part(const unsigned short* __restrict__ Qg,
               const unsigned short* __restrict__ Kg,
               const unsigned short* __restrict__ Vtg,
               unsigned short* __restrict__ Og,
               unsigned short* __restrict__ Pb,
               float* __restrict__ Pml) {
  const int bid = blockIdx.x;      // 0..511
  const int bh = bid & 31;         // bh%8 -> XCD: each bh's KV on one L2
  const int j  = bid >> 5;         // 0..15: which 17-tile run
  const int bb = bh >> 4, hh = bh & 15;
  const int tid = threadIdx.x, wid = tid >> 6, lane = tid & 63;
  const int l15 = lane & 15, lg = lane >> 4;
  const int wq = wid * 32;
  const size_t baseQ = (size_t)bb * Sn * Dn + (size_t)hh * DKn;
  const size_t baseV = (size_t)bh * DKn * Sn;

  __shared__ unsigned short Ks[2][64 * 64];   // K tile  [key][d], dbuf
  __shared__ unsigned short Vts[2][64 * 64];  // Vt tile [d][key], dbuf
  __shared__ unsigned short Ps[4][32 * 72];   // per-wave P [q][key], pad 72

  const int lrow  = lane >> 3;
  const int sgran = (lane & 7) ^ lrow;
  const int swz   = l15 & 7;

  // locate starting segment
  const int g0 = 17 * j;
  int qt = 0;
  while ((qt + 1) * (qt + 2) <= g0) ++qt;
  int kt = g0 - qt * (qt + 1);     // kv-tile index within segment

  int sqt = qt, skt = kt;
  auto stage = [&](int t, int b) {
    const int k0 = t << 6;
#pragma unroll
    for (int p = 0; p < 2; ++p) {
      int c = p * 4 + wid;
      int r = c * 8 + lrow;
      gload_lds16(Kg + baseQ + (size_t)(k0 + r) * Dn + sgran * 8, &Ks[b][c * 512]);
    }
#pragma unroll
    for (int p = 0; p < 2; ++p) {
      int c = p * 4 + wid;
      int dr = c * 8 + lrow;
      gload_lds16(Vtg + baseV + (size_t)dr * Sn + k0 + sgran * 8, &Vts[b][c * 512]);
    }
  };
  auto advs = [&]() { ++skt; if (skt == 2 * sqt + 2) { skt = 0; ++sqt; } };

  stage(skt, 0); advs();
  __syncthreads();

  bf16x8 qf[2][2];
  auto loadQ = [&](int qtile) {
    const int q0 = qtile * 128;
#pragma unroll
    for (int qm = 0; qm < 2; ++qm)
#pragma unroll
      for (int kd = 0; kd < 2; ++kd)
        qf[qm][kd] = *(const bf16x8*)(Qg + baseQ +
                     (size_t)(q0 + wq + qm * 16 + l15) * Dn + kd * 32 + lg * 8);
  };
  loadQ(qt);

  f32x4 oacc[2][4] = {};
  float mrun[2] = {-1e30f, -1e30f};
  float lrun[2] = {0.f, 0.f};
  int pstart = kt;                 // first kv-tile of current segment piece

  for (int i = 0; i < 17; ++i) {
    const int cur = i & 1;
    if (i < 16) { stage(skt, cur ^ 1); advs(); }
    const int k0 = kt << 6;
    const int q0 = qt * 128;

    if (k0 <= q0 + wq + 31) {      // wave-level causal skip
      f32x4 sf[2][4] = {};
      __builtin_amdgcn_s_setprio(1);
#pragma unroll
      for (int kn = 0; kn < 4; ++kn)
#pragma unroll
        for (int kd = 0; kd < 2; ++kd) {
          bf16x8 kf = *(const bf16x8*)(&Ks[cur][(kn * 16 + l15) * 64 +
                                              (((kd * 4 + lg) ^ swz) * 8)]);
          sf[0][kn] = mfma16(kf, qf[0][kd], sf[0][kn]);
          sf[1][kn] = mfma16(kf, qf[1][kd], sf[1][kn]);
        }
      __builtin_amdgcn_s_setprio(0);

      if (k0 + 63 > q0 + wq) {     // causal mask (diag-overlap tiles)
#pragma unroll
        for (int qm = 0; qm < 2; ++qm) {
          int qq = q0 + wq + qm * 16 + l15;
#pragma unroll
          for (int kn = 0; kn < 4; ++kn)
#pragma unroll
            for (int jj = 0; jj < 4; ++jj) {
              int key = k0 + kn * 16 + lg * 4 + jj;
              if (key > qq) sf[qm][kn][jj] = -1e30f;
            }
        }
      }

#pragma unroll
      for (int qm = 0; qm < 2; ++qm) {
        float t = sf[qm][0][0];
#pragma unroll
        for (int kn = 0; kn < 4; ++kn)
#pragma unroll
          for (int jj = 0; jj < 4; ++jj) t = fmaxf(t, sf[qm][kn][jj]);
        t = fmaxf(t, __shfl_xor(t, 16));
        t = fmaxf(t, __shfl_xor(t, 32));
        if (__any(t > mrun[qm] + 8.0f)) {       // defer-max THR=8
          float mnew = fmaxf(mrun[qm], t);
          float corr = __expf(mrun[qm] - mnew);
          mrun[qm] = mnew;
          lrun[qm] *= corr;
#pragma unroll
          for (int dn = 0; dn < 4; ++dn) oacc[qm][dn] *= corr;
        }
        const float m = mrun[qm];
        float rs = 0.f;
#pragma unroll
        for (int kn = 0; kn < 4; ++kn) {
#pragma unroll
          for (int jj = 0; jj < 4; ++jj) {
            float p = __expf(sf[qm][kn][jj] - m);
            sf[qm][kn][jj] = p;
            rs += p;
          }
          uint2 pw;
          pw.x = cvtpk(sf[qm][kn][0], sf[qm][kn][1]);
          pw.y = cvtpk(sf[qm][kn][2], sf[qm][kn][3]);
          *(uint2*)(&Ps[wid][(qm * 16 + l15) * 72 + kn * 16 + lg * 4]) = pw;
        }
        rs += __shfl_xor(rs, 16);
        rs += __shfl_xor(rs, 32);
        lrun[qm] += rs;
      }

      __builtin_amdgcn_s_setprio(1);
#pragma unroll
      for (int kk = 0; kk < 2; ++kk) {
        bf16x8 pf[2];
#pragma unroll
        for (int qm = 0; qm < 2; ++qm)
          pf[qm] = *(const bf16x8*)(&Ps[wid][(qm * 16 + l15) * 72 + kk * 32 + lg * 8]);
#pragma unroll
        for (int dn = 0; dn < 4; ++dn) {
          bf16x8 vf = *(const bf16x8*)(&Vts[cur][(dn * 16 + l15) * 64 +
                                               (((kk * 4 + lg) ^ swz) * 8)]);
#pragma unroll
          for (int qm = 0; qm < 2; ++qm)
            oacc[qm][dn] = mfma16(vf, pf[qm], oacc[qm][dn]);
        }
      }
      __builtin_amdgcn_s_setprio(0);
    }

    const bool segend = (kt == 2 * qt + 1);
    if (segend || i == 16) {
      if (pstart == 0 && segend) {
        // whole segment in this block: finalize to Og
#pragma unroll
        for (int qm = 0; qm < 2; ++qm) {
          float rinv = 1.0f / lrun[qm];
          int row = q0 + wq + qm * 16 + l15;
#pragma unroll
          for (int dn = 0; dn < 4; ++dn) {
            ushort4 ow;
            ow.x = f2bf(oacc[qm][dn][0] * rinv);
            ow.y = f2bf(oacc[qm][dn][1] * rinv);
            ow.z = f2bf(oacc[qm][dn][2] * rinv);
            ow.w = f2bf(oacc[qm][dn][3] * rinv);
            *(ushort4*)(Og + baseQ + (size_t)row * Dn + dn * 16 + lg * 4) = ow;
          }
        }
      } else {
        // partial: slot = ((bh*16+qt)*3 + ord)
        const int seg_s = qt * (qt + 1);
        const int ord = pstart ? ((seg_s + pstart) / 17 - seg_s / 17) : 0;
        const size_t slot = (size_t)((bh * 16 + qt) * 3 + ord);
#pragma unroll
        for (int qm = 0; qm < 2; ++qm) {
          int rl = wq + qm * 16 + l15;     // local row 0..127
#pragma unroll
          for (int dn = 0; dn < 4; ++dn) {
            ushort4 ow;
            ow.x = f2bf(oacc[qm][dn][0]);
            ow.y = f2bf(oacc[qm][dn][1]);
            ow.z = f2bf(oacc[qm][dn][2]);
            ow.w = f2bf(oacc[qm][dn][3]);
            *(ushort4*)(Pb + slot * 8192 + (size_t)rl * 64 + dn * 16 + lg * 4) = ow;
          }
          if (lg == 0) {
            Pml[slot * 256 + rl] = mrun[qm];
            Pml[slot * 256 + 128 + rl] = lrun[qm];
          }
        }
      }
      if (i < 16) {
        ++qt; kt = 0; pstart = 0;
        loadQ(qt);
#pragma unroll
        for (int qm = 0; qm < 2; ++qm) {
          mrun[qm] = -1e30f; lrun[qm] = 0.f;
#pragma unroll
          for (int dn = 0; dn < 4; ++dn) oacc[qm][dn] = f32x4{0.f, 0.f, 0.f, 0.f};
        }
      }
    } else {
      ++kt;
    }
    __syncthreads();
  }
}

// ---------------------------------------------------------------------------
// Merge partials for split segments.
// ---------------------------------------------------------------------------
__global__ __launch_bounds__(256)
void attn_combine(const unsigned short* __restrict__ Pb,
                  const float* __restrict__ Pml,
                  unsigned short* __restrict__ Og) {
  const int b = blockIdx.x;        // bh*16 + qt
  const int bh = b >> 4, qt = b & 15;
  const int seg_s = qt * (qt + 1);
  const int seg_e = seg_s + 2 * qt + 2;
  const int c0 = (seg_s / 17 + 1) * 17;
  if (c0 >= seg_e) return;         // not split
  const int np = (c0 + 17 < seg_e) ? 3 : 2;
  const int bb = bh >> 4, hh = bh & 15;
  const size_t baseQ = (size_t)bb * Sn * Dn + (size_t)hh * DKn;
  const int q0 = qt * 128;
  const int slot0 = b * 3;
  const int r = threadIdx.x >> 1;          // 0..127
  const int c32 = (threadIdx.x & 1) * 32;  // col half

  float m0 = Pml[(size_t)slot0 * 256 + r];
  float l0 = Pml[(size_t)slot0 * 256 + 128 + r];
  float m1 = Pml[(size_t)(slot0 + 1) * 256 + r];
  float l1 = Pml[(size_t)(slot0 + 1) * 256 + 128 + r];
  float m2 = -1e30f, l2 = 0.f;
  if (np == 3) {
    m2 = Pml[(size_t)(slot0 + 2) * 256 + r];
    l2 = Pml[(size_t)(slot0 + 2) * 256 + 128 + r];
  }
  float M = fmaxf(fmaxf(m0, m1), m2);
  float w0 = __expf(m0 - M), w1 = __expf(m1 - M);
  float w2 = (np == 3) ? __expf(m2 - M) : 0.f;
  float L = l0 * w0 + l1 * w1 + l2 * w2;

  float acc[32];
#pragma unroll
  for (int k = 0; k < 32; ++k) acc[k] = 0.f;

  auto accum = [&](int p, float w) {
    const unsigned short* src = Pb + (size_t)(slot0 + p) * 8192 + (size_t)r * 64 + c32;
#pragma unroll
    for (int k4 = 0; k4 < 8; ++k4) {
      ushort4 v = *(const ushort4*)(src + k4 * 4);
      acc[k4 * 4 + 0] += w * bf2f(v.x);
      acc[k4 * 4 + 1] += w * bf2f(v.y);
      acc[k4 * 4 + 2] += w * bf2f(v.z);
      acc[k4 * 4 + 3] += w * bf2f(v.w);
    }
  };
  accum(0, w0);
  accum(1, w1);
  if (np == 3) accum(2, w2);

  float rinv = 1.0f / L;
#pragma unroll
  for (int k4 = 0; k4 < 8; ++k4) {
    ushort4 o;
    o.x = f2bf(acc[k4 * 4 + 0] * rinv);
    o.y = f2bf(acc[k4 * 4 + 1] * rinv);
    o.z = f2bf(acc[k4 * 4 + 2] * rinv);
    o.w = f2bf(acc[k4 * 4 + 3] * rinv);
    *(ushort4*)(Og + baseQ + (size_t)(q0 + r) * Dn + c32 + k4 * 4) = o;
  }
}

// ---------------------------------------------------------------------------
extern "C" void kernel_launch(void* const* d_in, const int* in_sizes, int n_in,
                              void* d_out, int out_size, void* d_ws, size_t ws_size,
                              hipStream_t stream) {
  const float* x  = (const float*)d_in[0];
  const float* Wq = (const float*)d_in[1];
  const float* Wk = (const float*)d_in[2];
  const float* Wv = (const float*)d_in[3];
  const float* Wo = (const float*)d_in[4];
  float* out = (float*)d_out;

  char* ws = (char*)d_ws;
  size_t off = 0;
  unsigned short* xb  = (unsigned short*)(ws + off); off += (size_t)Mrows * Dn * 2;
  unsigned short* wqb = (unsigned short*)(ws + off); off += (size_t)Dn * Dn * 2;
  unsigned short* wkb = (unsigned short*)(ws + off); off += (size_t)Dn * Dn * 2;
  unsigned short* wvb = (unsigned short*)(ws + off); off += (size_t)Dn * Dn * 2;
  unsigned short* wob = (unsigned short*)(ws + off); off += (size_t)Dn * Dn * 2;
  unsigned short* Qb  = (unsigned short*)(ws + off); off += (size_t)Mrows * Dn * 2;
  unsigned short* Kb  = (unsigned short*)(ws + off); off += (size_t)Mrows * Dn * 2;
  unsigned short* Vtb = (unsigned short*)(ws + off); off += (size_t)Mrows * Dn * 2;
  unsigned short* Ob  = (unsigned short*)(ws + off); off += (size_t)Mrows * Dn * 2;
  unsigned short* Pb  = (unsigned short*)(ws + off); off += (size_t)512 * 3 * 8192 * 2;
  float*          Pml = (float*)(ws + off);          off += (size_t)512 * 3 * 256 * 4;

  cvt_all<<<8192, 256, 0, stream>>>(x, Wq, Wk, Wv, Wo, xb, wqb, wkb, wvb, wob);
  gemm_qkv<<<dim3(Mrows / 128, Dn / 128, 3), 256, 0, stream>>>(xb, wqb, wkb, wvb, Qb, Kb, Vtb);
  attn_part<<<512, 256, 0, stream>>>(Qb, Kb, Vtb, Ob, Pb, Pml);
  attn_combine<<<512, 256, 0, stream>>>(Pb, Pml, Ob);
  gemm_out<<<dim3(Mrows / 128, Dn / 128), 256, 0, stream>>>(Ob, wob, out);
}

// Round 8
// 112.179 us; speedup vs baseline: 2.2716x; 1.0536x over previous
//
#include <hip/hip_runtime.h>
#include <hip/hip_bf16.h>

typedef __attribute__((ext_vector_type(4))) float f32x4;
typedef __attribute__((ext_vector_type(8))) short bf16x8;

// Problem constants (B=2, S=2048, D=1024, H=16, DK=64)
#define Bn 2
#define Sn 2048
#define Dn 1024
#define Hn 16
#define DKn 64
#define Mrows (Bn * Sn)   // 4096

__device__ __forceinline__ unsigned short f2bf(float f) {
  unsigned int x = __float_as_uint(f);
  x += 0x7fffu + ((x >> 16) & 1u);   // round-to-nearest-even
  return (unsigned short)(x >> 16);
}

__device__ __forceinline__ float bf2f(unsigned short u) {
  return __uint_as_float(((unsigned int)u) << 16);
}

__device__ __forceinline__ unsigned int cvtpk(float lo, float hi) {
  unsigned int r;
  asm("v_cvt_pk_bf16_f32 %0, %1, %2" : "=v"(r) : "v"(lo), "v"(hi));
  return r;
}

__device__ __forceinline__ f32x4 mfma16(bf16x8 a, bf16x8 b, f32x4 c) {
  return __builtin_amdgcn_mfma_f32_16x16x32_bf16(a, b, c, 0, 0, 0);
}

__device__ __forceinline__ f32x4 max4(f32x4 a, f32x4 b) {
  f32x4 r;
  r[0] = fmaxf(a[0], b[0]); r[1] = fmaxf(a[1], b[1]);
  r[2] = fmaxf(a[2], b[2]); r[3] = fmaxf(a[3], b[3]);
  return r;
}

__device__ __forceinline__ void gload_lds16(const unsigned short* g, unsigned short* l) {
  __builtin_amdgcn_global_load_lds(
      (const __attribute__((address_space(1))) void*)g,
      (__attribute__((address_space(3))) void*)l, 16, 0, 0);
}

// ---------------------------------------------------------------------------
// fused fp32 -> bf16 convert for x + 4 weights (one launch)
// ---------------------------------------------------------------------------
__global__ __launch_bounds__(256)
void cvt_all(const float* __restrict__ x,  const float* __restrict__ wq,
             const float* __restrict__ wk, const float* __restrict__ wv,
             const float* __restrict__ wo,
             unsigned short* __restrict__ xb,  unsigned short* __restrict__ wqb,
             unsigned short* __restrict__ wkb, unsigned short* __restrict__ wvb,
             unsigned short* __restrict__ wob) {
  int i = (blockIdx.x * 256 + threadIdx.x) * 4;
  const float* src; unsigned short* dst; int off;
  int r = i >> 20;
  if (r < 4)       { src = x;  dst = xb;  off = i; }
  else if (r == 4) { src = wq; dst = wqb; off = i & 1048575; }
  else if (r == 5) { src = wk; dst = wkb; off = i & 1048575; }
  else if (r == 6) { src = wv; dst = wvb; off = i & 1048575; }
  else             { src = wo; dst = wob; off = i & 1048575; }
  float4 v = *(const float4*)(src + off);
  ushort4 o;
  o.x = f2bf(v.x); o.y = f2bf(v.y); o.z = f2bf(v.z); o.w = f2bf(v.w);
  *(ushort4*)(dst + off) = o;
}

// ---------------------------------------------------------------------------
// GEMM: C[M,N] = A[M,K] * W[N,K]^T  (bf16 in, fp32 accum)
// 128x128 tile, BK=32, 4 waves, TRIPLE-buffered LDS (48 KB -> 3 blocks/CU,
// all 768 co-resident).  One raw s_barrier per K-step + counted vmcnt(4)
// (2 stages always in flight).  Granule XOR swizzle g^((row>>1)&3): linear
// LDS dest (gload_lds), pre-swizzled global source, matching read XOR.
// MODE 0: bf16, scaled 0.125 (Q) | 1: bf16 (K) | 2: Vt[b][h][d][s] | 3: fp32
// ---------------------------------------------------------------------------
template<int MODE>
__device__ __forceinline__ void gemm_body(const unsigned short* __restrict__ A,
                                          const unsigned short* __restrict__ W,
                                          unsigned short* __restrict__ Cb,
                                          float* __restrict__ Cf,
                                          unsigned short* As,   // [3][128*32]
                                          unsigned short* Bs) { // [3][128*32]
  const int K = Dn, N = Dn;
  const int tid  = threadIdx.x;
  const int wid  = tid >> 6;
  const int lane = tid & 63;
  const int l15  = lane & 15;
  const int lg   = lane >> 4;
  const int row0 = blockIdx.x * 128;
  const int col0 = blockIdx.y * 128;
  const int wr = (wid >> 1) * 64;
  const int wc = (wid & 1) * 64;

  f32x4 acc[4][4] = {};

  // staging: chunk = 16 rows x 32 elems (1 KB) = one gload_lds per wave-instr
  const int lrow2 = lane >> 2;               // row within chunk 0..15
  const int gs    = (lane & 3) ^ ((lane >> 3) & 3);  // pre-swizzled src granule
  const int swzr  = (l15 >> 1) & 3;          // read-side XOR

  auto stage = [&](int kt, int b) {
#pragma unroll
    for (int q = 0; q < 2; ++q) {
      int chunk = wid * 2 + q;               // 0..7
      int r = chunk * 16 + lrow2;
      gload_lds16(A + (size_t)(row0 + r) * K + kt + gs * 8,
                  &As[b * 4096 + chunk * 512]);
    }
#pragma unroll
    for (int q = 0; q < 2; ++q) {
      int chunk = wid * 2 + q;
      int r = chunk * 16 + lrow2;
      gload_lds16(W + (size_t)(col0 + r) * K + kt + gs * 8,
                  &Bs[b * 4096 + chunk * 512]);
    }
  };

  auto compute = [&](int b) {
    bf16x8 af[4], bfr[4];
#pragma unroll
    for (int m = 0; m < 4; ++m)
      af[m] = *(const bf16x8*)(&As[b * 4096 + (wr + m * 16 + l15) * 32 +
                                   ((lg ^ swzr) * 8)]);
#pragma unroll
    for (int n = 0; n < 4; ++n)
      bfr[n] = *(const bf16x8*)(&Bs[b * 4096 + (wc + n * 16 + l15) * 32 +
                                    ((lg ^ swzr) * 8)]);
    __builtin_amdgcn_s_setprio(1);
#pragma unroll
    for (int m = 0; m < 4; ++m)
#pragma unroll
      for (int n = 0; n < 4; ++n)
        acc[m][n] = mfma16(af[m], bfr[n], acc[m][n]);
    __builtin_amdgcn_s_setprio(0);
  };

  stage(0, 0);
  stage(32, 1);
  int cb = 0;                                // compute buffer = t % 3
#pragma unroll 1
  for (int t = 0; t < 32; ++t) {
    if (t < 31) asm volatile("s_waitcnt vmcnt(4)" ::: "memory");
    else        asm volatile("s_waitcnt vmcnt(0)" ::: "memory");
    __builtin_amdgcn_sched_barrier(0);
    __builtin_amdgcn_s_barrier();
    __builtin_amdgcn_sched_barrier(0);
    if (t <= 29) {
      int sb = cb + 2; if (sb >= 3) sb -= 3;
      stage((t + 2) * 32, sb);
    }
    compute(cb);
    ++cb; if (cb == 3) cb = 0;
  }

#pragma unroll
  for (int m = 0; m < 4; ++m)
#pragma unroll
    for (int n = 0; n < 4; ++n) {
      int r0 = row0 + wr + m * 16 + lg * 4;
      int c  = col0 + wc + n * 16 + l15;
      if (MODE == 2) {
        int b = r0 >> 11, s = r0 & 2047;
        int h = c >> 6,  d = c & 63;
        ushort4 pw;
        pw.x = f2bf(acc[m][n][0]); pw.y = f2bf(acc[m][n][1]);
        pw.z = f2bf(acc[m][n][2]); pw.w = f2bf(acc[m][n][3]);
        *(ushort4*)(Cb + ((((size_t)b * Hn + h) * DKn + d) << 11) + s) = pw;
      } else {
#pragma unroll
        for (int j = 0; j < 4; ++j) {
          size_t idx = (size_t)(r0 + j) * N + c;
          float v = acc[m][n][j];
          if (MODE == 3)      Cf[idx] = v;
          else if (MODE == 0) Cb[idx] = f2bf(v * 0.125f);
          else                Cb[idx] = f2bf(v);
        }
      }
    }
}

__global__ __launch_bounds__(256, 3)
void gemm_qkv(const unsigned short* __restrict__ A,
              const unsigned short* __restrict__ W0,
              const unsigned short* __restrict__ W1,
              const unsigned short* __restrict__ W2,
              unsigned short* __restrict__ C0,
              unsigned short* __restrict__ C1,
              unsigned short* __restrict__ C2) {
  __shared__ unsigned short As[3 * 128 * 32];
  __shared__ unsigned short Bs[3 * 128 * 32];
  if (blockIdx.z == 0)      gemm_body<0>(A, W0, C0, nullptr, As, Bs);
  else if (blockIdx.z == 1) gemm_body<1>(A, W1, C1, nullptr, As, Bs);
  else                      gemm_body<2>(A, W2, C2, nullptr, As, Bs);
}

__global__ __launch_bounds__(256, 3)
void gemm_out(const unsigned short* __restrict__ A,
              const unsigned short* __restrict__ W,
              float* __restrict__ C) {
  __shared__ unsigned short As[3 * 128 * 32];
  __shared__ unsigned short Bs[3 * 128 * 32];
  gemm_body<3>(A, W, nullptr, C, As, Bs);
}

// ---------------------------------------------------------------------------
// Flash attention (causal), swapped-operand, UNIFORM KV-SPLIT, 768 blocks.
// Per bh: 272 flat KV tiles over 24 blocks; block j covers [34j/3, 34(j+1)/3)
// (11-12 tiles).  3 blocks/CU resident.  Whole segments finalize to Og;
// pieces: seg-initial -> slot bh*40+qt, block-initial continuing -> slot
// bh*40+16+j (block j has at most one).  attn_combine merges <=4 pieces.
// Softmax: tree max/sum (depth 4), defer-max THR=8, cvt_pk P pack.
// ---------------------------------------------------------------------------
__global__ __launch_bounds__(256, 3)
void attn_part(const unsigned short* __restrict__ Qg,
               const unsigned short* __restrict__ Kg,
               const unsigned short* __restrict__ Vtg,
               unsigned short* __restrict__ Og,
               unsigned short* __restrict__ Pb,
               float* __restrict__ Pml) {
  const int bid = blockIdx.x;      // 0..767
  const int bh = bid & 31;         // bh%8 -> XCD locality
  const int j  = bid >> 5;         // 0..23
  const int bb = bh >> 4, hh = bh & 15;
  const int tid = threadIdx.x, wid = tid >> 6, lane = tid & 63;
  const int l15 = lane & 15, lg = lane >> 4;
  const int wq = wid * 32;
  const size_t baseQ = (size_t)bb * Sn * Dn + (size_t)hh * DKn;
  const size_t baseV = (size_t)bh * DKn * Sn;

  __shared__ unsigned short Ks[2][64 * 64];   // K tile  [key][d], dbuf
  __shared__ unsigned short Vts[2][64 * 64];  // Vt tile [d][key], dbuf
  __shared__ unsigned short Ps[4][32 * 72];   // per-wave P [q][key], pad 72

  const int lrow  = lane >> 3;
  const int sgran = (lane & 7) ^ lrow;
  const int swz   = l15 & 7;

  const int bstart = (34 * j) / 3;
  const int nt = (34 * (j + 1)) / 3 - bstart;

  int qt = 0;
  while ((qt + 1) * (qt + 2) <= bstart) ++qt;
  int kt = bstart - qt * (qt + 1);

  int sqt = qt, skt = kt;
  auto stage = [&](int t, int b) {
    const int k0 = t << 6;
#pragma unroll
    for (int p = 0; p < 2; ++p) {
      int c = p * 4 + wid;
      int r = c * 8 + lrow;
      gload_lds16(Kg + baseQ + (size_t)(k0 + r) * Dn + sgran * 8, &Ks[b][c * 512]);
    }
#pragma unroll
    for (int p = 0; p < 2; ++p) {
      int c = p * 4 + wid;
      int dr = c * 8 + lrow;
      gload_lds16(Vtg + baseV + (size_t)dr * Sn + k0 + sgran * 8, &Vts[b][c * 512]);
    }
  };
  auto advs = [&]() { ++skt; if (skt == 2 * sqt + 2) { skt = 0; ++sqt; } };

  stage(skt, 0); advs();
  __syncthreads();

  bf16x8 qf[2][2];
  auto loadQ = [&](int qtile) {
    const int q0 = qtile * 128;
#pragma unroll
    for (int qm = 0; qm < 2; ++qm)
#pragma unroll
      for (int kd = 0; kd < 2; ++kd)
        qf[qm][kd] = *(const bf16x8*)(Qg + baseQ +
                     (size_t)(q0 + wq + qm * 16 + l15) * Dn + kd * 32 + lg * 8);
  };
  loadQ(qt);

  f32x4 oacc[2][4] = {};
  float mrun[2] = {-1e30f, -1e30f};
  float lrun[2] = {0.f, 0.f};
  int pstart = kt;                 // first kv-tile of current piece

  for (int i = 0; i < nt; ++i) {
    const int cur = i & 1;
    if (i < nt - 1) { stage(skt, cur ^ 1); advs(); }
    const int k0 = kt << 6;
    const int q0 = qt * 128;

    if (k0 <= q0 + wq + 31) {      // wave-level causal skip
      f32x4 sf[2][4] = {};
      __builtin_amdgcn_s_setprio(1);
#pragma unroll
      for (int kn = 0; kn < 4; ++kn)
#pragma unroll
        for (int kd = 0; kd < 2; ++kd) {
          bf16x8 kf = *(const bf16x8*)(&Ks[cur][(kn * 16 + l15) * 64 +
                                              (((kd * 4 + lg) ^ swz) * 8)]);
          sf[0][kn] = mfma16(kf, qf[0][kd], sf[0][kn]);
          sf[1][kn] = mfma16(kf, qf[1][kd], sf[1][kn]);
        }
      __builtin_amdgcn_s_setprio(0);

      if (k0 + 63 > q0 + wq) {     // causal mask (diag-overlap tiles)
#pragma unroll
        for (int qm = 0; qm < 2; ++qm) {
          int qq = q0 + wq + qm * 16 + l15;
#pragma unroll
          for (int kn = 0; kn < 4; ++kn)
#pragma unroll
            for (int jj = 0; jj < 4; ++jj) {
              int key = k0 + kn * 16 + lg * 4 + jj;
              if (key > qq) sf[qm][kn][jj] = -1e30f;
            }
        }
      }

#pragma unroll
      for (int qm = 0; qm < 2; ++qm) {
        f32x4 mm = max4(max4(sf[qm][0], sf[qm][1]), max4(sf[qm][2], sf[qm][3]));
        float t = fmaxf(fmaxf(mm[0], mm[1]), fmaxf(mm[2], mm[3]));
        t = fmaxf(t, __shfl_xor(t, 16));
        t = fmaxf(t, __shfl_xor(t, 32));
        if (__any(t > mrun[qm] + 8.0f)) {       // defer-max THR=8
          float mnew = fmaxf(mrun[qm], t);
          float corr = __expf(mrun[qm] - mnew);
          mrun[qm] = mnew;
          lrun[qm] *= corr;
#pragma unroll
          for (int dn = 0; dn < 4; ++dn) oacc[qm][dn] *= corr;
        }
        const float m = mrun[qm];
#pragma unroll
        for (int kn = 0; kn < 4; ++kn) {
#pragma unroll
          for (int jj = 0; jj < 4; ++jj)
            sf[qm][kn][jj] = __expf(sf[qm][kn][jj] - m);
          uint2 pw;
          pw.x = cvtpk(sf[qm][kn][0], sf[qm][kn][1]);
          pw.y = cvtpk(sf[qm][kn][2], sf[qm][kn][3]);
          *(uint2*)(&Ps[wid][(qm * 16 + l15) * 72 + kn * 16 + lg * 4]) = pw;
        }
        f32x4 sv = (sf[qm][0] + sf[qm][1]) + (sf[qm][2] + sf[qm][3]);
        float rs = (sv[0] + sv[1]) + (sv[2] + sv[3]);
        rs += __shfl_xor(rs, 16);
        rs += __shfl_xor(rs, 32);
        lrun[qm] += rs;
      }

      __builtin_amdgcn_s_setprio(1);
#pragma unroll
      for (int kk = 0; kk < 2; ++kk) {
        bf16x8 pf[2];
#pragma unroll
        for (int qm = 0; qm < 2; ++qm)
          pf[qm] = *(const bf16x8*)(&Ps[wid][(qm * 16 + l15) * 72 + kk * 32 + lg * 8]);
#pragma unroll
        for (int dn = 0; dn < 4; ++dn) {
          bf16x8 vf = *(const bf16x8*)(&Vts[cur][(dn * 16 + l15) * 64 +
                                               (((kk * 4 + lg) ^ swz) * 8)]);
#pragma unroll
          for (int qm = 0; qm < 2; ++qm)
            oacc[qm][dn] = mfma16(vf, pf[qm], oacc[qm][dn]);
        }
      }
      __builtin_amdgcn_s_setprio(0);
    }

    const bool segend = (kt == 2 * qt + 1);
    if (segend || i == nt - 1) {
      if (pstart == 0 && segend) {
        // whole segment: finalize to Og
#pragma unroll
        for (int qm = 0; qm < 2; ++qm) {
          float rinv = 1.0f / lrun[qm];
          int row = q0 + wq + qm * 16 + l15;
#pragma unroll
          for (int dn = 0; dn < 4; ++dn) {
            ushort4 ow;
            ow.x = f2bf(oacc[qm][dn][0] * rinv);
            ow.y = f2bf(oacc[qm][dn][1] * rinv);
            ow.z = f2bf(oacc[qm][dn][2] * rinv);
            ow.w = f2bf(oacc[qm][dn][3] * rinv);
            *(ushort4*)(Og + baseQ + (size_t)row * Dn + dn * 16 + lg * 4) = ow;
          }
        }
      } else {
        // piece: seg-initial -> slot qt; continuing -> slot 16+j
        const size_t slot = (size_t)bh * 40 + (pstart == 0 ? qt : 16 + j);
#pragma unroll
        for (int qm = 0; qm < 2; ++qm) {
          int rl = wq + qm * 16 + l15;     // local row 0..127
#pragma unroll
          for (int dn = 0; dn < 4; ++dn) {
            ushort4 ow;
            ow.x = f2bf(oacc[qm][dn][0]);
            ow.y = f2bf(oacc[qm][dn][1]);
            ow.z = f2bf(oacc[qm][dn][2]);
            ow.w = f2bf(oacc[qm][dn][3]);
            *(ushort4*)(Pb + slot * 8192 + (size_t)rl * 64 + dn * 16 + lg * 4) = ow;
          }
          if (lg == 0) {
            Pml[slot * 256 + rl] = mrun[qm];
            Pml[slot * 256 + 128 + rl] = lrun[qm];
          }
        }
      }
      if (i < nt - 1) {
        ++qt; kt = 0; pstart = 0;
        loadQ(qt);
#pragma unroll
        for (int qm = 0; qm < 2; ++qm) {
          mrun[qm] = -1e30f; lrun[qm] = 0.f;
#pragma unroll
          for (int dn = 0; dn < 4; ++dn) oacc[qm][dn] = f32x4{0.f, 0.f, 0.f, 0.f};
        }
      }
    } else {
      ++kt;
    }
    __syncthreads();
  }
}

// ---------------------------------------------------------------------------
// Merge <=4 pieces for split segments.  One block per (bh,qt).
// ---------------------------------------------------------------------------
__global__ __launch_bounds__(256)
void attn_combine(const unsigned short* __restrict__ Pb,
                  const float* __restrict__ Pml,
                  unsigned short* __restrict__ Og) {
  const int b = blockIdx.x;        // bh*16 + qt
  const int bh = b >> 4, qt = b & 15;
  const int s = qt * (qt + 1);
  const int e = s + 2 * qt + 2;
  const int js = (3 * s + 2) / 34;
  const int je = (3 * (e - 1) + 2) / 34;
  const int np = je - js + 1;
  if (np == 1) return;             // whole segment finalized in attn_part
  const int bb = bh >> 4, hh = bh & 15;
  const size_t baseQ = (size_t)bb * Sn * Dn + (size_t)hh * DKn;
  const int q0 = qt * 128;
  const int r = threadIdx.x >> 1;          // 0..127
  const int c32 = (threadIdx.x & 1) * 32;  // col half

  const size_t s0 = (size_t)bh * 40 + qt;
  const size_t s1 = (size_t)bh * 40 + 16 + js + 1;
  const size_t s2 = (size_t)bh * 40 + 16 + js + 2;
  const size_t s3 = (size_t)bh * 40 + 16 + js + 3;

  float m0 = Pml[s0 * 256 + r],      l0 = Pml[s0 * 256 + 128 + r];
  float m1 = Pml[s1 * 256 + r],      l1 = Pml[s1 * 256 + 128 + r];
  float m2 = -1e30f, l2 = 0.f, m3 = -1e30f, l3 = 0.f;
  if (np > 2) { m2 = Pml[s2 * 256 + r]; l2 = Pml[s2 * 256 + 128 + r]; }
  if (np > 3) { m3 = Pml[s3 * 256 + r]; l3 = Pml[s3 * 256 + 128 + r]; }

  float M = fmaxf(fmaxf(m0, m1), fmaxf(m2, m3));
  float w0 = __expf(m0 - M), w1 = __expf(m1 - M);
  float w2 = (np > 2) ? __expf(m2 - M) : 0.f;
  float w3 = (np > 3) ? __expf(m3 - M) : 0.f;
  float L = l0 * w0 + l1 * w1 + l2 * w2 + l3 * w3;

  float acc[32];
#pragma unroll
  for (int k = 0; k < 32; ++k) acc[k] = 0.f;

  auto accum = [&](size_t slot, float w) {
    const unsigned short* src = Pb + slot * 8192 + (size_t)r * 64 + c32;
#pragma unroll
    for (int k4 = 0; k4 < 8; ++k4) {
      ushort4 v = *(const ushort4*)(src + k4 * 4);
      acc[k4 * 4 + 0] += w * bf2f(v.x);
      acc[k4 * 4 + 1] += w * bf2f(v.y);
      acc[k4 * 4 + 2] += w * bf2f(v.z);
      acc[k4 * 4 + 3] += w * bf2f(v.w);
    }
  };
  accum(s0, w0);
  accum(s1, w1);
  if (np > 2) accum(s2, w2);
  if (np > 3) accum(s3, w3);

  float rinv = 1.0f / L;
#pragma unroll
  for (int k4 = 0; k4 < 8; ++k4) {
    ushort4 o;
    o.x = f2bf(acc[k4 * 4 + 0] * rinv);
    o.y = f2bf(acc[k4 * 4 + 1] * rinv);
    o.z = f2bf(acc[k4 * 4 + 2] * rinv);
    o.w = f2bf(acc[k4 * 4 + 3] * rinv);
    *(ushort4*)(Og + baseQ + (size_t)(q0 + r) * Dn + c32 + k4 * 4) = o;
  }
}

// ---------------------------------------------------------------------------
extern "C" void kernel_launch(void* const* d_in, const int* in_sizes, int n_in,
                              void* d_out, int out_size, void* d_ws, size_t ws_size,
                              hipStream_t stream) {
  const float* x  = (const float*)d_in[0];
  const float* Wq = (const float*)d_in[1];
  const float* Wk = (const float*)d_in[2];
  const float* Wv = (const float*)d_in[3];
  const float* Wo = (const float*)d_in[4];
  float* out = (float*)d_out;

  char* ws = (char*)d_ws;
  size_t off = 0;
  unsigned short* xb  = (unsigned short*)(ws + off); off += (size_t)Mrows * Dn * 2;
  unsigned short* wqb = (unsigned short*)(ws + off); off += (size_t)Dn * Dn * 2;
  unsigned short* wkb = (unsigned short*)(ws + off); off += (size_t)Dn * Dn * 2;
  unsigned short* wvb = (unsigned short*)(ws + off); off += (size_t)Dn * Dn * 2;
  unsigned short* wob = (unsigned short*)(ws + off); off += (size_t)Dn * Dn * 2;
  unsigned short* Qb  = (unsigned short*)(ws + off); off += (size_t)Mrows * Dn * 2;
  unsigned short* Kb  = (unsigned short*)(ws + off); off += (size_t)Mrows * Dn * 2;
  unsigned short* Vtb = (unsigned short*)(ws + off); off += (size_t)Mrows * Dn * 2;
  unsigned short* Ob  = (unsigned short*)(ws + off); off += (size_t)Mrows * Dn * 2;
  unsigned short* Pb  = (unsigned short*)(ws + off); off += (size_t)1280 * 8192 * 2;
  float*          Pml = (float*)(ws + off);          off += (size_t)1280 * 256 * 4;

  cvt_all<<<8192, 256, 0, stream>>>(x, Wq, Wk, Wv, Wo, xb, wqb, wkb, wvb, wob);
  gemm_qkv<<<dim3(Mrows / 128, Dn / 128, 3), 256, 0, stream>>>(xb, wqb, wkb, wvb, Qb, Kb, Vtb);
  attn_part<<<768, 256, 0, stream>>>(Qb, Kb, Vtb, Ob, Pb, Pml);
  attn_combine<<<512, 256, 0, stream>>>(Pb, Pml, Ob);
  gemm_out<<<dim3(Mrows / 128, Dn / 128), 256, 0, stream>>>(Ob, wob, out);
}

// Round 9
// 109.753 us; speedup vs baseline: 2.3218x; 1.0221x over previous
//
#include <hip/hip_runtime.h>
#include <hip/hip_bf16.h>

typedef __attribute__((ext_vector_type(4))) float f32x4;
typedef __attribute__((ext_vector_type(8))) short bf16x8;

// Problem constants (B=2, S=2048, D=1024, H=16, DK=64)
#define Bn 2
#define Sn 2048
#define Dn 1024
#define Hn 16
#define DKn 64
#define Mrows (Bn * Sn)   // 4096

__device__ __forceinline__ unsigned short f2bf(float f) {
  unsigned int x = __float_as_uint(f);
  x += 0x7fffu + ((x >> 16) & 1u);   // round-to-nearest-even
  return (unsigned short)(x >> 16);
}

__device__ __forceinline__ float bf2f(unsigned short u) {
  return __uint_as_float(((unsigned int)u) << 16);
}

__device__ __forceinline__ unsigned int cvtpk(float lo, float hi) {
  unsigned int r;
  asm("v_cvt_pk_bf16_f32 %0, %1, %2" : "=v"(r) : "v"(lo), "v"(hi));
  return r;
}

__device__ __forceinline__ float exp2a(float x) {   // native v_exp_f32 (2^x)
  float r;
  asm("v_exp_f32 %0, %1" : "=v"(r) : "v"(x));
  return r;
}

__device__ __forceinline__ f32x4 mfma16(bf16x8 a, bf16x8 b, f32x4 c) {
  return __builtin_amdgcn_mfma_f32_16x16x32_bf16(a, b, c, 0, 0, 0);
}

__device__ __forceinline__ f32x4 max4(f32x4 a, f32x4 b) {
  f32x4 r;
  r[0] = fmaxf(a[0], b[0]); r[1] = fmaxf(a[1], b[1]);
  r[2] = fmaxf(a[2], b[2]); r[3] = fmaxf(a[3], b[3]);
  return r;
}

__device__ __forceinline__ void gload_lds16(const unsigned short* g, unsigned short* l) {
  __builtin_amdgcn_global_load_lds(
      (const __attribute__((address_space(1))) void*)g,
      (__attribute__((address_space(3))) void*)l, 16, 0, 0);
}

// ---------------------------------------------------------------------------
// fused fp32 -> bf16 convert for x + 4 weights (one launch)
// ---------------------------------------------------------------------------
__global__ __launch_bounds__(256)
void cvt_all(const float* __restrict__ x,  const float* __restrict__ wq,
             const float* __restrict__ wk, const float* __restrict__ wv,
             const float* __restrict__ wo,
             unsigned short* __restrict__ xb,  unsigned short* __restrict__ wqb,
             unsigned short* __restrict__ wkb, unsigned short* __restrict__ wvb,
             unsigned short* __restrict__ wob) {
  int i = (blockIdx.x * 256 + threadIdx.x) * 4;
  const float* src; unsigned short* dst; int off;
  int r = i >> 20;
  if (r < 4)       { src = x;  dst = xb;  off = i; }
  else if (r == 4) { src = wq; dst = wqb; off = i & 1048575; }
  else if (r == 5) { src = wk; dst = wkb; off = i & 1048575; }
  else if (r == 6) { src = wv; dst = wvb; off = i & 1048575; }
  else             { src = wo; dst = wob; off = i & 1048575; }
  float4 v = *(const float4*)(src + off);
  ushort4 o;
  o.x = f2bf(v.x); o.y = f2bf(v.y); o.z = f2bf(v.z); o.w = f2bf(v.w);
  *(ushort4*)(dst + off) = o;
}

// ---------------------------------------------------------------------------
// GEMM: C[M,N] = A[M,K] * W[N,K]^T  (bf16 in, fp32 accum)
// 128x128 tile, BK=32, 4 waves, TRIPLE-buffered LDS, counted vmcnt(4).
// MODE 0: bf16, scaled 0.125*log2(e) (Q in exp2 domain) | 1: bf16 (K)
// MODE 2: Vt[b][h][d][s] | 3: fp32 out
// ---------------------------------------------------------------------------
template<int MODE>
__device__ __forceinline__ void gemm_body(const unsigned short* __restrict__ A,
                                          const unsigned short* __restrict__ W,
                                          unsigned short* __restrict__ Cb,
                                          float* __restrict__ Cf,
                                          unsigned short* As,   // [3][128*32]
                                          unsigned short* Bs) { // [3][128*32]
  const int K = Dn, N = Dn;
  const int tid  = threadIdx.x;
  const int wid  = tid >> 6;
  const int lane = tid & 63;
  const int l15  = lane & 15;
  const int lg   = lane >> 4;
  const int row0 = blockIdx.x * 128;
  const int col0 = blockIdx.y * 128;
  const int wr = (wid >> 1) * 64;
  const int wc = (wid & 1) * 64;

  f32x4 acc[4][4] = {};

  const int lrow2 = lane >> 2;               // row within chunk 0..15
  const int gs    = (lane & 3) ^ ((lane >> 3) & 3);  // pre-swizzled src granule
  const int swzr  = (l15 >> 1) & 3;          // read-side XOR

  auto stage = [&](int kt, int b) {
#pragma unroll
    for (int q = 0; q < 2; ++q) {
      int chunk = wid * 2 + q;               // 0..7
      int r = chunk * 16 + lrow2;
      gload_lds16(A + (size_t)(row0 + r) * K + kt + gs * 8,
                  &As[b * 4096 + chunk * 512]);
    }
#pragma unroll
    for (int q = 0; q < 2; ++q) {
      int chunk = wid * 2 + q;
      int r = chunk * 16 + lrow2;
      gload_lds16(W + (size_t)(col0 + r) * K + kt + gs * 8,
                  &Bs[b * 4096 + chunk * 512]);
    }
  };

  auto compute = [&](int b) {
    bf16x8 af[4], bfr[4];
#pragma unroll
    for (int m = 0; m < 4; ++m)
      af[m] = *(const bf16x8*)(&As[b * 4096 + (wr + m * 16 + l15) * 32 +
                                   ((lg ^ swzr) * 8)]);
#pragma unroll
    for (int n = 0; n < 4; ++n)
      bfr[n] = *(const bf16x8*)(&Bs[b * 4096 + (wc + n * 16 + l15) * 32 +
                                    ((lg ^ swzr) * 8)]);
    __builtin_amdgcn_s_setprio(1);
#pragma unroll
    for (int m = 0; m < 4; ++m)
#pragma unroll
      for (int n = 0; n < 4; ++n)
        acc[m][n] = mfma16(af[m], bfr[n], acc[m][n]);
    __builtin_amdgcn_s_setprio(0);
  };

  stage(0, 0);
  stage(32, 1);
  int cb = 0;
#pragma unroll 1
  for (int t = 0; t < 32; ++t) {
    if (t < 31) asm volatile("s_waitcnt vmcnt(4)" ::: "memory");
    else        asm volatile("s_waitcnt vmcnt(0)" ::: "memory");
    __builtin_amdgcn_sched_barrier(0);
    __builtin_amdgcn_s_barrier();
    __builtin_amdgcn_sched_barrier(0);
    if (t <= 29) {
      int sb = cb + 2; if (sb >= 3) sb -= 3;
      stage((t + 2) * 32, sb);
    }
    compute(cb);
    ++cb; if (cb == 3) cb = 0;
  }

#pragma unroll
  for (int m = 0; m < 4; ++m)
#pragma unroll
    for (int n = 0; n < 4; ++n) {
      int r0 = row0 + wr + m * 16 + lg * 4;
      int c  = col0 + wc + n * 16 + l15;
      if (MODE == 2) {
        int b = r0 >> 11, s = r0 & 2047;
        int h = c >> 6,  d = c & 63;
        ushort4 pw;
        pw.x = f2bf(acc[m][n][0]); pw.y = f2bf(acc[m][n][1]);
        pw.z = f2bf(acc[m][n][2]); pw.w = f2bf(acc[m][n][3]);
        *(ushort4*)(Cb + ((((size_t)b * Hn + h) * DKn + d) << 11) + s) = pw;
      } else {
#pragma unroll
        for (int j = 0; j < 4; ++j) {
          size_t idx = (size_t)(r0 + j) * N + c;
          float v = acc[m][n][j];
          if (MODE == 3)      Cf[idx] = v;
          else if (MODE == 0) Cb[idx] = f2bf(v * 0.18033688f);  // 0.125*log2(e)
          else                Cb[idx] = f2bf(v);
        }
      }
    }
}

__global__ __launch_bounds__(256, 3)
void gemm_qkv(const unsigned short* __restrict__ A,
              const unsigned short* __restrict__ W0,
              const unsigned short* __restrict__ W1,
              const unsigned short* __restrict__ W2,
              unsigned short* __restrict__ C0,
              unsigned short* __restrict__ C1,
              unsigned short* __restrict__ C2) {
  __shared__ unsigned short As[3 * 128 * 32];
  __shared__ unsigned short Bs[3 * 128 * 32];
  if (blockIdx.z == 0)      gemm_body<0>(A, W0, C0, nullptr, As, Bs);
  else if (blockIdx.z == 1) gemm_body<1>(A, W1, C1, nullptr, As, Bs);
  else                      gemm_body<2>(A, W2, C2, nullptr, As, Bs);
}

__global__ __launch_bounds__(256, 3)
void gemm_out(const unsigned short* __restrict__ A,
              const unsigned short* __restrict__ W,
              float* __restrict__ C) {
  __shared__ unsigned short As[3 * 128 * 32];
  __shared__ unsigned short Bs[3 * 128 * 32];
  gemm_body<3>(A, W, nullptr, C, As, Bs);
}

// ---------------------------------------------------------------------------
// Flash attention (causal), swapped-operand, UNIFORM KV-SPLIT, 768 blocks.
// exp2-domain softmax (Q pre-scaled by 0.125*log2e).  Per-tile common path
// has NO cross-lane ops: lane-local max check (__any), deferred per-lane
// sum (reduced once at piece writeout), native v_exp_f32.
// ---------------------------------------------------------------------------
__global__ __launch_bounds__(256, 3)
void attn_part(const unsigned short* __restrict__ Qg,
               const unsigned short* __restrict__ Kg,
               const unsigned short* __restrict__ Vtg,
               unsigned short* __restrict__ Og,
               unsigned short* __restrict__ Pb,
               float* __restrict__ Pml) {
  const int bid = blockIdx.x;      // 0..767
  const int bh = bid & 31;         // bh%8 -> XCD locality
  const int j  = bid >> 5;         // 0..23
  const int bb = bh >> 4, hh = bh & 15;
  const int tid = threadIdx.x, wid = tid >> 6, lane = tid & 63;
  const int l15 = lane & 15, lg = lane >> 4;
  const int wq = wid * 32;
  const size_t baseQ = (size_t)bb * Sn * Dn + (size_t)hh * DKn;
  const size_t baseV = (size_t)bh * DKn * Sn;

  __shared__ unsigned short Ks[2][64 * 64];   // K tile  [key][d], dbuf
  __shared__ unsigned short Vts[2][64 * 64];  // Vt tile [d][key], dbuf
  __shared__ unsigned short Ps[4][32 * 72];   // per-wave P [q][key], pad 72

  const int lrow  = lane >> 3;
  const int sgran = (lane & 7) ^ lrow;
  const int swz   = l15 & 7;

  const int bstart = (34 * j) / 3;
  const int nt = (34 * (j + 1)) / 3 - bstart;

  int qt = 0;
  while ((qt + 1) * (qt + 2) <= bstart) ++qt;
  int kt = bstart - qt * (qt + 1);

  int sqt = qt, skt = kt;
  auto stage = [&](int t, int b) {
    const int k0 = t << 6;
#pragma unroll
    for (int p = 0; p < 2; ++p) {
      int c = p * 4 + wid;
      int r = c * 8 + lrow;
      gload_lds16(Kg + baseQ + (size_t)(k0 + r) * Dn + sgran * 8, &Ks[b][c * 512]);
    }
#pragma unroll
    for (int p = 0; p < 2; ++p) {
      int c = p * 4 + wid;
      int dr = c * 8 + lrow;
      gload_lds16(Vtg + baseV + (size_t)dr * Sn + k0 + sgran * 8, &Vts[b][c * 512]);
    }
  };
  auto advs = [&]() { ++skt; if (skt == 2 * sqt + 2) { skt = 0; ++sqt; } };

  stage(skt, 0); advs();
  __syncthreads();

  bf16x8 qf[2][2];
  auto loadQ = [&](int qtile) {
    const int q0 = qtile * 128;
#pragma unroll
    for (int qm = 0; qm < 2; ++qm)
#pragma unroll
      for (int kd = 0; kd < 2; ++kd)
        qf[qm][kd] = *(const bf16x8*)(Qg + baseQ +
                     (size_t)(q0 + wq + qm * 16 + l15) * Dn + kd * 32 + lg * 8);
  };
  loadQ(qt);

  f32x4 oacc[2][4] = {};
  float mrun[2] = {-1e30f, -1e30f};
  float lrun[2] = {0.f, 0.f};     // per-lane partial (deferred cross-lane sum)
  int pstart = kt;                 // first kv-tile of current piece

  for (int i = 0; i < nt; ++i) {
    const int cur = i & 1;
    if (i < nt - 1) { stage(skt, cur ^ 1); advs(); }
    const int k0 = kt << 6;
    const int q0 = qt * 128;

    if (k0 <= q0 + wq + 31) {      // wave-level causal skip
      f32x4 sf[2][4] = {};
      __builtin_amdgcn_s_setprio(1);
#pragma unroll
      for (int kn = 0; kn < 4; ++kn)
#pragma unroll
        for (int kd = 0; kd < 2; ++kd) {
          bf16x8 kf = *(const bf16x8*)(&Ks[cur][(kn * 16 + l15) * 64 +
                                              (((kd * 4 + lg) ^ swz) * 8)]);
          sf[0][kn] = mfma16(kf, qf[0][kd], sf[0][kn]);
          sf[1][kn] = mfma16(kf, qf[1][kd], sf[1][kn]);
        }
      __builtin_amdgcn_s_setprio(0);

      if (k0 + 63 > q0 + wq) {     // causal mask (diag-overlap tiles)
#pragma unroll
        for (int qm = 0; qm < 2; ++qm) {
          int qq = q0 + wq + qm * 16 + l15;
#pragma unroll
          for (int kn = 0; kn < 4; ++kn)
#pragma unroll
            for (int jj = 0; jj < 4; ++jj) {
              int key = k0 + kn * 16 + lg * 4 + jj;
              if (key > qq) sf[qm][kn][jj] = -1e30f;
            }
        }
      }

#pragma unroll
      for (int qm = 0; qm < 2; ++qm) {
        // lane-local max of own 16 values (no cross-lane in common path)
        f32x4 mm = max4(max4(sf[qm][0], sf[qm][1]), max4(sf[qm][2], sf[qm][3]));
        float tl = fmaxf(fmaxf(mm[0], mm[1]), fmaxf(mm[2], mm[3]));
        if (__any(tl > mrun[qm] + 11.5f)) {   // defer-max THR (log2 domain)
          float t = tl;
          t = fmaxf(t, __shfl_xor(t, 16));
          t = fmaxf(t, __shfl_xor(t, 32));
          float mnew = fmaxf(mrun[qm], t);
          float corr = exp2a(mrun[qm] - mnew);
          mrun[qm] = mnew;
          lrun[qm] *= corr;
#pragma unroll
          for (int dn = 0; dn < 4; ++dn) oacc[qm][dn] *= corr;
        }
        const float m = mrun[qm];
#pragma unroll
        for (int kn = 0; kn < 4; ++kn) {
#pragma unroll
          for (int jj = 0; jj < 4; ++jj)
            sf[qm][kn][jj] = exp2a(sf[qm][kn][jj] - m);
          uint2 pw;
          pw.x = cvtpk(sf[qm][kn][0], sf[qm][kn][1]);
          pw.y = cvtpk(sf[qm][kn][2], sf[qm][kn][3]);
          *(uint2*)(&Ps[wid][(qm * 16 + l15) * 72 + kn * 16 + lg * 4]) = pw;
        }
        f32x4 sv = (sf[qm][0] + sf[qm][1]) + (sf[qm][2] + sf[qm][3]);
        lrun[qm] += (sv[0] + sv[1]) + (sv[2] + sv[3]);   // per-lane partial
      }

      __builtin_amdgcn_s_setprio(1);
#pragma unroll
      for (int kk = 0; kk < 2; ++kk) {
        bf16x8 pf[2];
#pragma unroll
        for (int qm = 0; qm < 2; ++qm)
          pf[qm] = *(const bf16x8*)(&Ps[wid][(qm * 16 + l15) * 72 + kk * 32 + lg * 8]);
#pragma unroll
        for (int dn = 0; dn < 4; ++dn) {
          bf16x8 vf = *(const bf16x8*)(&Vts[cur][(dn * 16 + l15) * 64 +
                                               (((kk * 4 + lg) ^ swz) * 8)]);
#pragma unroll
          for (int qm = 0; qm < 2; ++qm)
            oacc[qm][dn] = mfma16(vf, pf[qm], oacc[qm][dn]);
        }
      }
      __builtin_amdgcn_s_setprio(0);
    }

    const bool segend = (kt == 2 * qt + 1);
    if (segend || i == nt - 1) {
      if (pstart == 0 && segend) {
        // whole segment: finalize to Og
#pragma unroll
        for (int qm = 0; qm < 2; ++qm) {
          float lt = lrun[qm];                 // cross-lane sum (once per seg)
          lt += __shfl_xor(lt, 16);
          lt += __shfl_xor(lt, 32);
          float rinv = 1.0f / lt;
          int row = q0 + wq + qm * 16 + l15;
#pragma unroll
          for (int dn = 0; dn < 4; ++dn) {
            ushort4 ow;
            ow.x = f2bf(oacc[qm][dn][0] * rinv);
            ow.y = f2bf(oacc[qm][dn][1] * rinv);
            ow.z = f2bf(oacc[qm][dn][2] * rinv);
            ow.w = f2bf(oacc[qm][dn][3] * rinv);
            *(ushort4*)(Og + baseQ + (size_t)row * Dn + dn * 16 + lg * 4) = ow;
          }
        }
      } else {
        // piece: seg-initial -> slot qt; continuing -> slot 16+j
        const size_t slot = (size_t)bh * 40 + (pstart == 0 ? qt : 16 + j);
#pragma unroll
        for (int qm = 0; qm < 2; ++qm) {
          float lt = lrun[qm];
          lt += __shfl_xor(lt, 16);
          lt += __shfl_xor(lt, 32);
          int rl = wq + qm * 16 + l15;     // local row 0..127
#pragma unroll
          for (int dn = 0; dn < 4; ++dn) {
            ushort4 ow;
            ow.x = f2bf(oacc[qm][dn][0]);
            ow.y = f2bf(oacc[qm][dn][1]);
            ow.z = f2bf(oacc[qm][dn][2]);
            ow.w = f2bf(oacc[qm][dn][3]);
            *(ushort4*)(Pb + slot * 8192 + (size_t)rl * 64 + dn * 16 + lg * 4) = ow;
          }
          if (lg == 0) {
            Pml[slot * 256 + rl] = mrun[qm];
            Pml[slot * 256 + 128 + rl] = lt;
          }
        }
      }
      if (i < nt - 1) {
        ++qt; kt = 0; pstart = 0;
        loadQ(qt);
#pragma unroll
        for (int qm = 0; qm < 2; ++qm) {
          mrun[qm] = -1e30f; lrun[qm] = 0.f;
#pragma unroll
          for (int dn = 0; dn < 4; ++dn) oacc[qm][dn] = f32x4{0.f, 0.f, 0.f, 0.f};
        }
      }
    } else {
      ++kt;
    }
    __syncthreads();
  }
}

// ---------------------------------------------------------------------------
// Merge <=4 pieces for split segments (exp2-domain weights).
// ---------------------------------------------------------------------------
__global__ __launch_bounds__(256)
void attn_combine(const unsigned short* __restrict__ Pb,
                  const float* __restrict__ Pml,
                  unsigned short* __restrict__ Og) {
  const int b = blockIdx.x;        // bh*16 + qt
  const int bh = b >> 4, qt = b & 15;
  const int s = qt * (qt + 1);
  const int e = s + 2 * qt + 2;
  const int js = (3 * s + 2) / 34;
  const int je = (3 * (e - 1) + 2) / 34;
  const int np = je - js + 1;
  if (np == 1) return;             // whole segment finalized in attn_part
  const int bb = bh >> 4, hh = bh & 15;
  const size_t baseQ = (size_t)bb * Sn * Dn + (size_t)hh * DKn;
  const int q0 = qt * 128;
  const int r = threadIdx.x >> 1;          // 0..127
  const int c32 = (threadIdx.x & 1) * 32;  // col half

  const size_t s0 = (size_t)bh * 40 + qt;
  const size_t s1 = (size_t)bh * 40 + 16 + js + 1;
  const size_t s2 = (size_t)bh * 40 + 16 + js + 2;
  const size_t s3 = (size_t)bh * 40 + 16 + js + 3;

  float m0 = Pml[s0 * 256 + r],      l0 = Pml[s0 * 256 + 128 + r];
  float m1 = Pml[s1 * 256 + r],      l1 = Pml[s1 * 256 + 128 + r];
  float m2 = -1e30f, l2 = 0.f, m3 = -1e30f, l3 = 0.f;
  if (np > 2) { m2 = Pml[s2 * 256 + r]; l2 = Pml[s2 * 256 + 128 + r]; }
  if (np > 3) { m3 = Pml[s3 * 256 + r]; l3 = Pml[s3 * 256 + 128 + r]; }

  float M = fmaxf(fmaxf(m0, m1), fmaxf(m2, m3));
  float w0 = exp2a(m0 - M), w1 = exp2a(m1 - M);
  float w2 = (np > 2) ? exp2a(m2 - M) : 0.f;
  float w3 = (np > 3) ? exp2a(m3 - M) : 0.f;
  float L = l0 * w0 + l1 * w1 + l2 * w2 + l3 * w3;

  float acc[32];
#pragma unroll
  for (int k = 0; k < 32; ++k) acc[k] = 0.f;

  auto accum = [&](size_t slot, float w) {
    const unsigned short* src = Pb + slot * 8192 + (size_t)r * 64 + c32;
#pragma unroll
    for (int k4 = 0; k4 < 8; ++k4) {
      ushort4 v = *(const ushort4*)(src + k4 * 4);
      acc[k4 * 4 + 0] += w * bf2f(v.x);
      acc[k4 * 4 + 1] += w * bf2f(v.y);
      acc[k4 * 4 + 2] += w * bf2f(v.z);
      acc[k4 * 4 + 3] += w * bf2f(v.w);
    }
  };
  accum(s0, w0);
  accum(s1, w1);
  if (np > 2) accum(s2, w2);
  if (np > 3) accum(s3, w3);

  float rinv = 1.0f / L;
#pragma unroll
  for (int k4 = 0; k4 < 8; ++k4) {
    ushort4 o;
    o.x = f2bf(acc[k4 * 4 + 0] * rinv);
    o.y = f2bf(acc[k4 * 4 + 1] * rinv);
    o.z = f2bf(acc[k4 * 4 + 2] * rinv);
    o.w = f2bf(acc[k4 * 4 + 3] * rinv);
    *(ushort4*)(Og + baseQ + (size_t)(q0 + r) * Dn + c32 + k4 * 4) = o;
  }
}

// ---------------------------------------------------------------------------
extern "C" void kernel_launch(void* const* d_in, const int* in_sizes, int n_in,
                              void* d_out, int out_size, void* d_ws, size_t ws_size,
                              hipStream_t stream) {
  const float* x  = (const float*)d_in[0];
  const float* Wq = (const float*)d_in[1];
  const float* Wk = (const float*)d_in[2];
  const float* Wv = (const float*)d_in[3];
  const float* Wo = (const float*)d_in[4];
  float* out = (float*)d_out;

  char* ws = (char*)d_ws;
  size_t off = 0;
  unsigned short* xb  = (unsigned short*)(ws + off); off += (size_t)Mrows * Dn * 2;
  unsigned short* wqb = (unsigned short*)(ws + off); off += (size_t)Dn * Dn * 2;
  unsigned short* wkb = (unsigned short*)(ws + off); off += (size_t)Dn * Dn * 2;
  unsigned short* wvb = (unsigned short*)(ws + off); off += (size_t)Dn * Dn * 2;
  unsigned short* wob = (unsigned short*)(ws + off); off += (size_t)Dn * Dn * 2;
  unsigned short* Qb  = (unsigned short*)(ws + off); off += (size_t)Mrows * Dn * 2;
  unsigned short* Kb  = (unsigned short*)(ws + off); off += (size_t)Mrows * Dn * 2;
  unsigned short* Vtb = (unsigned short*)(ws + off); off += (size_t)Mrows * Dn * 2;
  unsigned short* Ob  = (unsigned short*)(ws + off); off += (size_t)Mrows * Dn * 2;
  unsigned short* Pb  = (unsigned short*)(ws + off); off += (size_t)1280 * 8192 * 2;
  float*          Pml = (float*)(ws + off);          off += (size_t)1280 * 256 * 4;

  cvt_all<<<8192, 256, 0, stream>>>(x, Wq, Wk, Wv, Wo, xb, wqb, wkb, wvb, wob);
  gemm_qkv<<<dim3(Mrows / 128, Dn / 128, 3), 256, 0, stream>>>(xb, wqb, wkb, wvb, Qb, Kb, Vtb);
  attn_part<<<768, 256, 0, stream>>>(Qb, Kb, Vtb, Ob, Pb, Pml);
  attn_combine<<<512, 256, 0, stream>>>(Pb, Pml, Ob);
  gemm_out<<<dim3(Mrows / 128, Dn / 128), 256, 0, stream>>>(Ob, wob, out);
}